// Round 5
// baseline (478.480 us; speedup 1.0000x reference)
//
#include <hip/hip_runtime.h>

typedef unsigned short u16;
typedef __attribute__((ext_vector_type(8))) short bf16x8;
typedef __attribute__((ext_vector_type(4))) float f32x4;

__device__ __forceinline__ float bf2f(u16 u){
  union { unsigned int i; float f; } x; x.i = ((unsigned int)u) << 16; return x.f;
}
__device__ __forceinline__ u16 f2bf(float f){
  union { float f; unsigned int i; } x; x.f = f;
  unsigned int r = x.i + 0x7fffu + ((x.i >> 16) & 1u);
  return (u16)(r >> 16);
}

// ---------------- f32 -> bf16 convert (vectorized) ----------------
__global__ __launch_bounds__(256) void cvt_f32_bf16(const float* __restrict__ in,
                                                    u16* __restrict__ out, int n4){
  int i = blockIdx.x*256 + threadIdx.x;
  if (i < n4){
    float4 v = reinterpret_cast<const float4*>(in)[i];
    ushort4 o = make_ushort4(f2bf(v.x), f2bf(v.y), f2bf(v.z), f2bf(v.w));
    reinterpret_cast<ushort4*>(out)[i] = o;
  }
}

// ---------------- conv weight transpose: w[2304][7] -> wtb[7][2304] bf16 -----
__global__ __launch_bounds__(256) void conv_prep(const float* __restrict__ w,
                                                 u16* __restrict__ wtb){
  int i = blockIdx.x*256 + threadIdx.x;
  if (i < 2304*7){
    int ch = i / 7, t = i % 7;
    wtb[t*2304 + ch] = f2bf(w[i]);
  }
}

// ======== 256-tile 2-phase double-buffered bf16 MFMA GEMM (512 thr) =========
// C[M][N] = A[M][K] * Bt[N][K]^T. BM=256, BK=64, 8 waves = 2(M) x 4(N).
// Wave tile 128 x (BN/4). One barrier per K-step: stage(next) issued BEFORE
// ds_read+MFMA(current); __syncthreads' implicit vmcnt(0) drain lands after
// ~1K cycles of MFMA. MODE 0: f32 out. MODE 2: split z/xbc/dt (gemm1).
template<int GUARD, int MODE, int BN>
__global__ __launch_bounds__(512,2) void gemm_big(
    const u16* __restrict__ A, int lda,
    const u16* __restrict__ Bt, int ldb,
    void* __restrict__ Cp, int ldc,
    int M, int N, int K,
    u16* __restrict__ zb, u16* __restrict__ xb, u16* __restrict__ db_)
{
  constexpr int NF   = BN/64;   // n-frags per wave (4 or 2)
  constexpr int BISS = BN/64;   // B stage issues (4 or 2)
  __shared__ __align__(16) u16 As[2][256*64];
  __shared__ __align__(16) u16 Bs[2][BN*64];
  const int tid = threadIdx.x;
  const int wid = tid >> 6;
  const int lane = tid & 63;
  // XCD-chunked bijective swizzle (grids are multiples of 8)
  const int nwg = gridDim.x * gridDim.y;
  const int bid = blockIdx.y * gridDim.x + blockIdx.x;
  const int q8  = nwg >> 3;
  const int swz = (bid & 7)*q8 + (bid >> 3);
  const int m0 = (swz / gridDim.x) * 256;
  const int n0 = (swz % gridDim.x) * BN;
  const int wm = wid >> 2;      // 0..1
  const int wn = wid & 3;       // 0..3
  const int lq = lane >> 4, lr = lane & 15;
  const int srow = tid >> 3;    // 0..63 (8 rows per wave per issue -> LDS dest
  const int scol = (tid & 7)*8; //        is wave-uniform base + lane*16B)

  f32x4 acc[8][NF];
  #pragma unroll
  for (int m=0;m<8;m++)
    #pragma unroll
    for (int n=0;n<NF;n++) acc[m][n] = (f32x4){0.f,0.f,0.f,0.f};

  auto stage = [&](int buf, int k0){
    #pragma unroll
    for (int i=0;i<4;i++){
      const u16* ga = A + (size_t)(m0 + i*64 + srow)*lda + k0 + scol;
      __builtin_amdgcn_global_load_lds(
        (const __attribute__((address_space(1))) void*)ga,
        (__attribute__((address_space(3))) void*)&As[buf][(i*64 + wid*8)*64], 16, 0, 0);
    }
    #pragma unroll
    for (int i=0;i<BISS;i++){
      int gn = n0 + i*64 + srow;
      if (GUARD) gn = (gn < N) ? gn : (N-1);
      const u16* gb = Bt + (size_t)gn*ldb + k0 + scol;
      __builtin_amdgcn_global_load_lds(
        (const __attribute__((address_space(1))) void*)gb,
        (__attribute__((address_space(3))) void*)&Bs[buf][(i*64 + wid*8)*64], 16, 0, 0);
    }
  };

  const int nt = K >> 6;
  stage(0, 0);
  __syncthreads();
  int cur = 0;
  for (int t=0; t<nt; ++t){
    if (t+1 < nt) stage(cur^1, (t+1)<<6);
    #pragma unroll
    for (int kk=0; kk<2; ++kk){
      bf16x8 af[8], bfr[NF];
      #pragma unroll
      for (int m=0;m<8;m++)
        af[m] = *reinterpret_cast<const bf16x8*>(&As[cur][(wm*128 + m*16 + lr)*64 + kk*32 + lq*8]);
      #pragma unroll
      for (int n=0;n<NF;n++)
        bfr[n] = *reinterpret_cast<const bf16x8*>(&Bs[cur][(wn*(BN/4) + n*16 + lr)*64 + kk*32 + lq*8]);
      #pragma unroll
      for (int m=0;m<8;m++)
        #pragma unroll
        for (int n=0;n<NF;n++)
          acc[m][n] = __builtin_amdgcn_mfma_f32_16x16x32_bf16(af[m], bfr[n], acc[m][n], 0,0,0);
    }
    __syncthreads();
    cur ^= 1;
  }

  #pragma unroll
  for (int m=0;m<8;m++){
    int row = m0 + wm*128 + m*16 + lq*4;
    #pragma unroll
    for (int n=0;n<NF;n++){
      int col = n0 + wn*(BN/4) + n*16 + lr;
      if (!GUARD || col < N){
        #pragma unroll
        for (int j=0;j<4;j++){
          float v = acc[m][n][j];
          size_t r = (size_t)(row+j);
          if (MODE == 0)      ((float*)Cp)[r*ldc + col] = v;
          else if (MODE == 1) ((u16*)Cp)[r*ldc + col] = f2bf(v);
          else {
            u16 bv = f2bf(v);
            if (col < 2048)      zb[r*2048 + col] = bv;
            else if (col < 4352) xb[r*2304 + (col-2048)] = bv;
            else                 db_[r*64 + (col-4352)] = bv;
          }
        }
      }
    }
  }
}

// ---------------- old 128-tile GEMM (kept for the skinny Dscal matmul) ------
template<int GUARD, int MODE>
__global__ __launch_bounds__(256) void gemm_bt(
    const u16* __restrict__ A, int lda,
    const u16* __restrict__ Bt, int ldb,
    void* __restrict__ Cp, int ldc,
    int M, int N, int K,
    u16* __restrict__ zb, u16* __restrict__ xb, u16* __restrict__ db_)
{
  __shared__ __align__(16) u16 As[128*64];
  __shared__ __align__(16) u16 Bs[128*64];
  const int tid  = threadIdx.x;
  const int wid  = tid >> 6;
  const int lane = tid & 63;
  const int nwg = gridDim.x * gridDim.y;
  const int bid = blockIdx.y * gridDim.x + blockIdx.x;
  const int q8  = nwg >> 3;
  const int swz = (bid & 7)*q8 + (bid >> 3);
  const int m0 = (swz / gridDim.x) * 128;
  const int n0 = (swz % gridDim.x) * 128;
  const int wr = wid >> 1, wc = wid & 1;
  const int lq = lane >> 4, lr = lane & 15;

  f32x4 acc[4][4];
  #pragma unroll
  for (int m=0;m<4;m++)
    #pragma unroll
    for (int n=0;n<4;n++) acc[m][n] = (f32x4){0.f,0.f,0.f,0.f};

  const int srow = wid*32 + (lane>>3);
  const int scol = (lane&7)*8;

  for (int k0=0; k0<K; k0+=64){
    #pragma unroll
    for (int i=0;i<4;i++){
      const u16* ga = A + (size_t)(m0 + srow + i*8)*lda + k0 + scol;
      __builtin_amdgcn_global_load_lds(
        (const __attribute__((address_space(1))) void*)ga,
        (__attribute__((address_space(3))) void*)&As[(wid*32+i*8)*64], 16, 0, 0);
    }
    #pragma unroll
    for (int i=0;i<4;i++){
      int gn = n0 + srow + i*8;
      if (GUARD) gn = (gn < N) ? gn : (N-1);
      const u16* gb = Bt + (size_t)gn*ldb + k0 + scol;
      __builtin_amdgcn_global_load_lds(
        (const __attribute__((address_space(1))) void*)gb,
        (__attribute__((address_space(3))) void*)&Bs[(wid*32+i*8)*64], 16, 0, 0);
    }
    __syncthreads();
    #pragma unroll
    for (int kk=0;kk<2;kk++){
      bf16x8 af[4], bfr[4];
      #pragma unroll
      for (int m=0;m<4;m++)
        af[m] = *reinterpret_cast<const bf16x8*>(&As[(wr*64 + m*16 + lr)*64 + kk*32 + lq*8]);
      #pragma unroll
      for (int n=0;n<4;n++)
        bfr[n] = *reinterpret_cast<const bf16x8*>(&Bs[(wc*64 + n*16 + lr)*64 + kk*32 + lq*8]);
      #pragma unroll
      for (int m=0;m<4;m++)
        #pragma unroll
        for (int n=0;n<4;n++)
          acc[m][n] = __builtin_amdgcn_mfma_f32_16x16x32_bf16(af[m], bfr[n], acc[m][n], 0,0,0);
    }
    __syncthreads();
  }

  #pragma unroll
  for (int m=0;m<4;m++){
    int row = m0 + wr*64 + m*16 + lq*4;
    #pragma unroll
    for (int n=0;n<4;n++){
      int col = n0 + wc*64 + n*16 + lr;
      if (!GUARD || col < N){
        #pragma unroll
        for (int j=0;j<4;j++){
          float v = acc[m][n][j];
          size_t r = (size_t)(row+j);
          if (MODE == 0)      ((float*)Cp)[r*ldc + col] = v;
          else if (MODE == 1) ((u16*)Cp)[r*ldc + col] = f2bf(v);
          else {
            u16 bv = f2bf(v);
            if (col < 2048)      zb[r*2048 + col] = bv;
            else if (col < 4352) xb[r*2304 + (col-2048)] = bv;
            else                 db_[r*64 + (col-4352)] = bv;
          }
        }
      }
    }
  }
}

// ---------------- depthwise conv7 (SAME) + bias + SiLU -> bf16 ----------------
__global__ __launch_bounds__(256) void conv_silu(
    const u16* __restrict__ xbc, const u16* __restrict__ wtb,
    const float* __restrict__ bias, u16* __restrict__ xc)
{
  const int bid = blockIdx.x;
  const int sb  = (bid & 7)*1152 + (bid >> 3);
  const int idx = sb*256 + threadIdx.x;       // < 8192*288
  const int g   = idx % 288;
  const int row = idx / 288;
  const int l = row & 4095;
  const int c = g*8;
  float a[8];
  float4 b0 = *reinterpret_cast<const float4*>(&bias[c]);
  float4 b1 = *reinterpret_cast<const float4*>(&bias[c+4]);
  a[0]=b0.x; a[1]=b0.y; a[2]=b0.z; a[3]=b0.w;
  a[4]=b1.x; a[5]=b1.y; a[6]=b1.z; a[7]=b1.w;
  #pragma unroll
  for (int t=0;t<7;t++){
    int ls = l + t - 3;
    if (ls >= 0 && ls < 4096){
      bf16x8 v  = *reinterpret_cast<const bf16x8*>(&xbc[(size_t)(row + t - 3)*2304 + c]);
      bf16x8 wv = *reinterpret_cast<const bf16x8*>(&wtb[t*2304 + c]);
      #pragma unroll
      for (int j=0;j<8;j++) a[j] += bf2f((u16)v[j]) * bf2f((u16)wv[j]);
    }
  }
  bf16x8 o;
  #pragma unroll
  for (int j=0;j<8;j++){
    float s = a[j]/(1.f+__expf(-a[j]));
    o[j] = (short)f2bf(s);
  }
  *reinterpret_cast<bf16x8*>(&xc[(size_t)row*2304 + c]) = o;
}

// ================= chunked SSD scan (Q=64) =================
__global__ __launch_bounds__(256) void ssd_chunk(
    const u16* __restrict__ xc, const u16* __restrict__ dtb,
    const float* __restrict__ dt_bias, const float* __restrict__ A_log,
    u16* __restrict__ yP, u16* __restrict__ dB, float* __restrict__ csum, int dir)
{
  const int c  = blockIdx.x & 63;
  const int th = blockIdx.x >> 6;
  const int h  = th & 31;
  const int b  = th >> 5;
  const int tid = threadIdx.x;
  const int wid = tid >> 6;
  const int lane = tid & 63;
  const int lq = lane >> 4, lr = lane & 15;

  __shared__ __align__(16) u16 Cs[64*64];
  __shared__ __align__(16) u16 Bls[64*64];
  __shared__ __align__(16) u16 Xt[64*64];
  __shared__ __align__(16) u16 Gm[64*64];
  __shared__ __align__(16) u16 Bwt[64*64];
  __shared__ float cum[64], dtl[64];

  const float Ah = -__expf(A_log[h]);

  for (int e = tid; e < 512; e += 256){
    int i = e >> 3, g = e & 7;
    int l = dir ? (4095 - (c*64+i)) : (c*64+i);
    size_t rb = (size_t)(b*4096 + l)*2304;
    *reinterpret_cast<bf16x8*>(&Bls[i*64+g*8]) =
        *reinterpret_cast<const bf16x8*>(&xc[rb + 2048 + dir*128 + g*8]);
    *reinterpret_cast<bf16x8*>(&Cs[i*64+g*8]) =
        *reinterpret_cast<const bf16x8*>(&xc[rb + 2112 + dir*128 + g*8]);
  }
  for (int e = tid; e < 512; e += 256){
    int i = e & 63, g = e >> 6;
    int l = dir ? (4095 - (c*64+i)) : (c*64+i);
    bf16x8 xv = *reinterpret_cast<const bf16x8*>(&xc[(size_t)(b*4096+l)*2304 + (size_t)h*64 + g*8]);
    #pragma unroll
    for (int j=0;j<8;j++) Xt[(g*8+j)*64 + i] = (u16)xv[j];
  }
  if (tid < 64){
    int i = tid;
    int l = dir ? (4095 - (c*64+i)) : (c*64+i);
    float raw = bf2f(dtb[(size_t)(b*4096+l)*64 + dir*32 + h]) + dt_bias[h];
    float dte = (raw > 20.f) ? raw : log1pf(__expf(raw));
    dtl[i] = dte;
    float s = dte;
    #pragma unroll
    for (int off=1; off<64; off<<=1){
      float o = __shfl_up(s, off, 64);
      if (i >= off) s += o;
    }
    cum[i] = s;
    if (i == 63) csum[blockIdx.x] = s;
  }
  __syncthreads();

  f32x4 g4[4];
  #pragma unroll
  for (int n=0;n<4;n++) g4[n] = (f32x4){0.f,0.f,0.f,0.f};
  #pragma unroll
  for (int kk=0;kk<2;kk++){
    bf16x8 ca = *reinterpret_cast<const bf16x8*>(&Cs[(wid*16+lr)*64 + kk*32 + lq*8]);
    #pragma unroll
    for (int n=0;n<4;n++){
      bf16x8 bb = *reinterpret_cast<const bf16x8*>(&Bls[(n*16+lr)*64 + kk*32 + lq*8]);
      g4[n] = __builtin_amdgcn_mfma_f32_16x16x32_bf16(ca, bb, g4[n], 0,0,0);
    }
  }
  #pragma unroll
  for (int n=0;n<4;n++){
    #pragma unroll
    for (int r=0;r<4;r++){
      int gi = wid*16 + lq*4 + r;
      int gj = n*16 + lr;
      float wgt = (gj <= gi) ? __expf(Ah*(cum[gi]-cum[gj]))*dtl[gj] : 0.f;
      Gm[gi*64+gj] = f2bf(g4[n][r]*wgt);
    }
  }
  float ctot = cum[63];
  for (int e = tid; e < 512; e += 256){
    int j = e & 63, g = e >> 6;
    float wj = __expf(Ah*(ctot - cum[j])) * dtl[j];
    bf16x8 bv = *reinterpret_cast<const bf16x8*>(&Bls[j*64 + g*8]);
    #pragma unroll
    for (int nn=0;nn<8;nn++) Bwt[(g*8+nn)*64 + j] = f2bf(wj * bf2f((u16)bv[nn]));
  }
  __syncthreads();

  f32x4 yi[4], db4[4];
  #pragma unroll
  for (int n=0;n<4;n++){ yi[n] = (f32x4){0.f,0.f,0.f,0.f}; db4[n] = (f32x4){0.f,0.f,0.f,0.f}; }
  #pragma unroll
  for (int kk=0;kk<2;kk++){
    bf16x8 ga = *reinterpret_cast<const bf16x8*>(&Gm[(wid*16+lr)*64 + kk*32 + lq*8]);
    bf16x8 xa = *reinterpret_cast<const bf16x8*>(&Xt[(wid*16+lr)*64 + kk*32 + lq*8]);
    #pragma unroll
    for (int n=0;n<4;n++){
      bf16x8 xb = *reinterpret_cast<const bf16x8*>(&Xt[(n*16+lr)*64 + kk*32 + lq*8]);
      yi[n] = __builtin_amdgcn_mfma_f32_16x16x32_bf16(ga, xb, yi[n], 0,0,0);
      bf16x8 wb = *reinterpret_cast<const bf16x8*>(&Bwt[(n*16+lr)*64 + kk*32 + lq*8]);
      db4[n] = __builtin_amdgcn_mfma_f32_16x16x32_bf16(xa, wb, db4[n], 0,0,0);
    }
  }
  #pragma unroll
  for (int n=0;n<4;n++){
    #pragma unroll
    for (int r=0;r<4;r++){
      int i = wid*16 + lq*4 + r;
      yP[(size_t)(b*4096 + c*64 + i)*2048 + (size_t)h*64 + n*16 + lr] = f2bf(yi[n][r]);
    }
  }
  u16* dst = dB + (size_t)blockIdx.x*4096;
  #pragma unroll
  for (int n=0;n<4;n++){
    #pragma unroll
    for (int r=0;r<4;r++){
      int p = wid*16 + lq*4 + r;
      dst[p*64 + n*16 + lr] = f2bf(db4[n][r]);
    }
  }
}

// Pass B1: sequential h-chain over chunks, slot-shift in-place.
__global__ __launch_bounds__(256) void ssd_state(
    u16* __restrict__ dB, const float* __restrict__ csum,
    const float* __restrict__ A_log)
{
  const int q = blockIdx.x & 3;
  const int task = blockIdx.x >> 2;
  const int h = task & 31;
  const float Ah = -__expf(A_log[h]);
  const int p  = q*16 + (threadIdx.x >> 4);
  const int nb = (threadIdx.x & 15) * 4;
  float h0=0.f, h1=0.f, h2=0.f, h3=0.f;
  for (int c=0; c<63; ++c){
    float P = __expf(Ah * csum[task*64 + c]);
    u16* ptr = dB + ((size_t)(task*64 + c))*4096 + p*64 + nb;
    ushort4 dv = *reinterpret_cast<const ushort4*>(ptr);
    h0 = P*h0 + bf2f(dv.x);
    h1 = P*h1 + bf2f(dv.y);
    h2 = P*h2 + bf2f(dv.z);
    h3 = P*h3 + bf2f(dv.w);
    *reinterpret_cast<ushort4*>(ptr) = make_ushort4(f2bf(h0),f2bf(h1),f2bf(h2),f2bf(h3));
  }
}

// Pass B2: y += cd[i] * (C @ h_in^T). chunk 0 skipped.
__global__ __launch_bounds__(256) void ssd_yinter(
    const u16* __restrict__ xc, const u16* __restrict__ dtb,
    const float* __restrict__ dt_bias, const float* __restrict__ A_log,
    const u16* __restrict__ dB, u16* __restrict__ yP, int dir)
{
  const int c  = blockIdx.x & 63;
  if (c == 0) return;
  const int th = blockIdx.x >> 6;
  const int h  = th & 31;
  const int b  = th >> 5;
  const int tid = threadIdx.x;
  const int wid = tid >> 6;
  const int lane = tid & 63;
  const int lq = lane >> 4, lr = lane & 15;

  __shared__ __align__(16) u16 Cs[64*64];
  __shared__ __align__(16) u16 Hs[64*64];
  __shared__ float cum[64];

  const float Ah = -__expf(A_log[h]);

  for (int e = tid; e < 512; e += 256){
    int i = e >> 3, g = e & 7;
    int l = dir ? (4095 - (c*64+i)) : (c*64+i);
    *reinterpret_cast<bf16x8*>(&Cs[i*64+g*8]) =
        *reinterpret_cast<const bf16x8*>(&xc[(size_t)(b*4096+l)*2304 + 2112 + dir*128 + g*8]);
    *reinterpret_cast<bf16x8*>(&Hs[e*8]) =
        *reinterpret_cast<const bf16x8*>(&dB[(size_t)(blockIdx.x-1)*4096 + e*8]);
  }
  if (tid < 64){
    int i = tid;
    int l = dir ? (4095 - (c*64+i)) : (c*64+i);
    float raw = bf2f(dtb[(size_t)(b*4096+l)*64 + dir*32 + h]) + dt_bias[h];
    float dte = (raw > 20.f) ? raw : log1pf(__expf(raw));
    float s = dte;
    #pragma unroll
    for (int off=1; off<64; off<<=1){
      float o = __shfl_up(s, off, 64);
      if (i >= off) s += o;
    }
    cum[i] = s;
  }
  __syncthreads();

  f32x4 acc[4];
  #pragma unroll
  for (int n=0;n<4;n++) acc[n] = (f32x4){0.f,0.f,0.f,0.f};
  #pragma unroll
  for (int kk=0;kk<2;kk++){
    bf16x8 ca = *reinterpret_cast<const bf16x8*>(&Cs[(wid*16+lr)*64 + kk*32 + lq*8]);
    #pragma unroll
    for (int n=0;n<4;n++){
      bf16x8 hb = *reinterpret_cast<const bf16x8*>(&Hs[(n*16+lr)*64 + kk*32 + lq*8]);
      acc[n] = __builtin_amdgcn_mfma_f32_16x16x32_bf16(ca, hb, acc[n], 0,0,0);
    }
  }
  #pragma unroll
  for (int n=0;n<4;n++){
    #pragma unroll
    for (int r=0;r<4;r++){
      int i = wid*16 + lq*4 + r;
      float cd = __expf(Ah*cum[i]);
      size_t a = (size_t)(b*4096 + c*64 + i)*2048 + (size_t)h*64 + n*16 + lr;
      yP[a] = f2bf(bf2f(yP[a]) + cd*acc[n][r]);
    }
  }
}

// ---------------- fuse: y-combine(shift/flip) + D*x + RMSNorm + SiLU(z) ------
__global__ __launch_bounds__(256) void fuse_rms(
    const u16* __restrict__ ypF, const u16* __restrict__ ypB,
    const u16* __restrict__ xc, const u16* __restrict__ zbuf,
    u16* __restrict__ un,
    const float* __restrict__ Dscal, const float* __restrict__ D_b,
    const float* __restrict__ rms_w)
{
  const int row = blockIdx.x;
  const int l = row & 4095;
  const int tid = threadIdx.x;
  const int c = tid*8;
  const int hh = tid >> 3;
  float v[8]; float ss = 0.f;
  const bool hasF = (l >= 1);
  const bool hasB = (l <= 4094);
  bf16x8 yf, yb;
  if (hasF) yf = *reinterpret_cast<const bf16x8*>(&ypF[(size_t)(row-1)*2048 + c]);
  if (hasB) yb = *reinterpret_cast<const bf16x8*>(&ypB[(size_t)(row + 4094 - 2*l)*2048 + c]);
  bf16x8 xv = *reinterpret_cast<const bf16x8*>(&xc[(size_t)row*2304 + c]);
  const float dsc = Dscal[(size_t)row*32 + hh] + D_b[hh];
  #pragma unroll
  for (int i=0;i<8;i++){
    float y = hasF ? bf2f((u16)yf[i]) : 0.f;
    if (hasB) y += bf2f((u16)yb[i]);
    y += dsc * bf2f((u16)xv[i]);
    v[i] = y;
    ss += y*y;
  }
  #pragma unroll
  for (int o=1;o<64;o<<=1) ss += __shfl_xor(ss, o, 64);
  __shared__ float sred[4];
  if ((tid & 63) == 0) sred[tid>>6] = ss;
  __syncthreads();
  float rstd = rsqrtf((sred[0]+sred[1]+sred[2]+sred[3]) * (1.f/2048.f) + 1e-5f);
  bf16x8 zv = *reinterpret_cast<const bf16x8*>(&zbuf[(size_t)row*2048 + c]);
  bf16x8 o;
  #pragma unroll
  for (int i=0;i<8;i++){
    float z = bf2f((u16)zv[i]);
    float sz = z / (1.f + __expf(-z));
    o[i] = (short)f2bf(v[i]*rstd*rms_w[c+i]*sz);
  }
  *reinterpret_cast<bf16x8*>(&un[(size_t)row*2048 + c]) = o;
}

extern "C" void kernel_launch(void* const* d_in, const int* in_sizes, int n_in,
                              void* d_out, int out_size, void* d_ws, size_t ws_size,
                              hipStream_t stream)
{
  const float* u       = (const float*)d_in[0];
  const float* w_in    = (const float*)d_in[1];
  const float* conv_w  = (const float*)d_in[2];
  const float* conv_b  = (const float*)d_in[3];
  const float* dt_bias = (const float*)d_in[4];
  const float* A_log   = (const float*)d_in[5];
  const float* D_w     = (const float*)d_in[6];
  const float* D_b     = (const float*)d_in[7];
  const float* rms_w   = (const float*)d_in[8];
  const float* w_out   = (const float*)d_in[9];
  float* out = (float*)d_out;
  (void)in_sizes; (void)n_in; (void)out_size; (void)ws_size;

  char* ws = (char*)d_ws;
  u16*   zbuf = (u16*)(ws);                         // 8192x2048 bf16
  u16*   xbc  = (u16*)(ws + 33554432);              // 8192x2304 bf16 (dead after conv -> dB -> un)
  u16*   dtbuf= (u16*)(ws + 71303168);              // 8192x64  bf16
  u16*   xc   = (u16*)(ws + 72351744);              // 8192x2304 bf16
  u16*   ypF  = (u16*)(ws + 110100480);             // 8192x2048 bf16
  u16*   ypB  = (u16*)(ws + 143654912);             // 8192x2048 bf16
  float* Dsc  = (float*)(ws + 177209344);           // 8192x32 f32
  u16*   w2b  = (u16*)(ws + 178257920);             // 1024x2048 bf16
  u16*   dwb  = (u16*)(ws + 182452224);             // 32x2048 bf16
  float* csum = (float*)(ws + 182583296);           // 2 x 4096 f32
  u16*   wtb  = (u16*)(ws + 182616064);             // 7x2304 bf16
  // aliases
  u16*   ub   = ypF;
  u16*   w1b  = ypF + (size_t)8192*1024;
  u16*   dB   = xbc;
  u16*   un   = xbc;

  cvt_f32_bf16<<<8192,256,0,stream>>>(u,     ub,  8192*1024/4);
  cvt_f32_bf16<<<4416,256,0,stream>>>(w_in,  w1b, 4416*1024/4);
  cvt_f32_bf16<<<2048,256,0,stream>>>(w_out, w2b, 1024*2048/4);
  cvt_f32_bf16<<<64,  256,0,stream>>>(D_w,   dwb, 32*2048/4);
  conv_prep<<<63,256,0,stream>>>(conv_w, wtb);

  // zxBCdt = u @ in_proj_w^T  (split into zbuf / xbc / dtbuf)
  gemm_big<1,2,256><<<dim3(18,32),512,0,stream>>>(ub,1024, w1b,1024, nullptr,0,
                                                  8192,4416,1024, zbuf, xbc, dtbuf);
  // depthwise conv + silu -> xc
  conv_silu<<<9216,256,0,stream>>>(xbc, wtb, conv_b, xc);
  // Dscal = x_og @ D_w^T  (f32)
  gemm_bt<1,0><<<dim3(1,64),256,0,stream>>>(xc,2304, dwb,2048, Dsc,32,
                                            8192,32,2048, nullptr,nullptr,nullptr);
  // chunked SSD scan, per direction
  for (int dir=0; dir<2; ++dir){
    u16* yP = dir ? ypB : ypF;
    ssd_chunk <<<4096,256,0,stream>>>(xc, dtbuf, dt_bias, A_log, yP, dB, csum + dir*4096, dir);
    ssd_state <<<256, 256,0,stream>>>(dB, csum + dir*4096, A_log);
    ssd_yinter<<<4096,256,0,stream>>>(xc, dtbuf, dt_bias, A_log, dB, yP, dir);
  }
  // combine + D path + RMS + gate -> un
  fuse_rms<<<8192,256,0,stream>>>(ypF, ypB, xc, zbuf, un, Dsc, D_b, rms_w);
  // out = un @ outproj_w^T  (f32)
  gemm_big<0,0,128><<<dim3(8,32),512,0,stream>>>(un,2048, w2b,2048, out,1024,
                                                 8192,1024,2048, nullptr,nullptr,nullptr);
}

// Round 6
// 463.090 us; speedup vs baseline: 1.0332x; 1.0332x over previous
//
#include <hip/hip_runtime.h>

typedef unsigned short u16;
typedef __attribute__((ext_vector_type(8))) short bf16x8;
typedef __attribute__((ext_vector_type(4))) float f32x4;

__device__ __forceinline__ float bf2f(u16 u){
  union { unsigned int i; float f; } x; x.i = ((unsigned int)u) << 16; return x.f;
}
__device__ __forceinline__ u16 f2bf(float f){
  union { float f; unsigned int i; } x; x.f = f;
  unsigned int r = x.i + 0x7fffu + ((x.i >> 16) & 1u);
  return (u16)(r >> 16);
}

// ---------------- f32 -> bf16 convert (vectorized) ----------------
__global__ __launch_bounds__(256) void cvt_f32_bf16(const float* __restrict__ in,
                                                    u16* __restrict__ out, int n4){
  int i = blockIdx.x*256 + threadIdx.x;
  if (i < n4){
    float4 v = reinterpret_cast<const float4*>(in)[i];
    ushort4 o = make_ushort4(f2bf(v.x), f2bf(v.y), f2bf(v.z), f2bf(v.w));
    reinterpret_cast<ushort4*>(out)[i] = o;
  }
}

// ---------------- conv weight transpose: w[2304][7] -> wtb[7][2304] bf16 -----
__global__ __launch_bounds__(256) void conv_prep(const float* __restrict__ w,
                                                 u16* __restrict__ wtb){
  int i = blockIdx.x*256 + threadIdx.x;
  if (i < 2304*7){
    int ch = i / 7, t = i % 7;
    wtb[t*2304 + ch] = f2bf(w[i]);
  }
}

// ====== counted-vmcnt pipelined bf16 MFMA GEMM (T3/T4), BK=32, 4 LDS bufs ===
// C[M][N] = A[M][K]*Bt[N][K]^T. NM x NN waves, wave tile (BM/NM) x (BN/NN).
// Pipeline: stage(t+3) issued after barrier(t); steady-state wait is
// vmcnt(8) (= 2 tiles x 4 loads/thread in flight), drain 8->4->0 at tail.
// T2 LDS swizzle in rule-#21 form: linear gload_lds dest + inverse-XOR'd
// GLOBAL source column-group + same XOR on ds_read (placement-only).
// MODE 0: f32 out. MODE 2: split z/xbc/dt (gemm1).
template<int GUARD, int MODE, int BM, int BN, int NM, int NN>
__global__ __launch_bounds__(64*NM*NN, 2) void gemm_p(
    const u16* __restrict__ A, int lda,
    const u16* __restrict__ Bt, int ldb,
    void* __restrict__ Cp, int ldc,
    int M, int N, int K,
    u16* __restrict__ zb, u16* __restrict__ xb, u16* __restrict__ db_)
{
  constexpr int T  = 64*NM*NN;
  constexpr int MF = BM/NM/16;
  constexpr int NF = BN/NN/16;
  __shared__ __align__(16) u16 As[4][BM*32];
  __shared__ __align__(16) u16 Bs[4][BN*32];
  const int tid  = threadIdx.x;
  const int wid  = tid >> 6;
  const int lane = tid & 63;
  // XCD-chunked bijective swizzle (grids are multiples of 8)
  const int nwg = gridDim.x * gridDim.y;
  const int bid = blockIdx.y * gridDim.x + blockIdx.x;
  const int q8  = nwg >> 3;
  const int swz = (bid & 7)*q8 + (bid >> 3);
  const int m0 = (swz / gridDim.x) * BM;
  const int n0 = (swz % gridDim.x) * BN;
  const int wm = wid / NN;
  const int wn = wid % NN;
  const int lq = lane >> 4, lr = lane & 15;
  // per-lane constant read-side XOR (row base is a multiple of 16)
  const int ce = (lq ^ ((lr&3) ^ ((lr>>2)&3))) * 8;

  f32x4 acc[MF][NF];
  #pragma unroll
  for (int m=0;m<MF;m++)
    #pragma unroll
    for (int n=0;n<NF;n++) acc[m][n] = (f32x4){0.f,0.f,0.f,0.f};

  auto stage = [&](int t){
    const int buf = t & 3;
    const int k0  = t << 5;
    #pragma unroll
    for (int i=0;i<(BM*4)/T;i++){
      int slot = i*T + tid;
      int row = slot >> 2, cg = slot & 3;
      int sc = cg ^ ((row&3) ^ ((row>>2)&3));
      const u16* ga = A + (size_t)(m0 + row)*lda + k0 + sc*8;
      __builtin_amdgcn_global_load_lds(
        (const __attribute__((address_space(1))) void*)ga,
        (__attribute__((address_space(3))) void*)&As[buf][slot*8], 16, 0, 0);
    }
    #pragma unroll
    for (int i=0;i<(BN*4)/T;i++){
      int slot = i*T + tid;
      int row = slot >> 2, cg = slot & 3;
      int gn = n0 + row;
      if (GUARD) gn = (gn < N) ? gn : (N-1);
      int sc = cg ^ ((row&3) ^ ((row>>2)&3));
      const u16* gb = Bt + (size_t)gn*ldb + k0 + sc*8;
      __builtin_amdgcn_global_load_lds(
        (const __attribute__((address_space(1))) void*)gb,
        (__attribute__((address_space(3))) void*)&Bs[buf][slot*8], 16, 0, 0);
    }
  };

  auto comp = [&](int t){
    const int buf = t & 3;
    bf16x8 af[MF], bfr[NF];
    #pragma unroll
    for (int m=0;m<MF;m++){
      int row = wm*(MF*16) + m*16 + lr;
      af[m] = *reinterpret_cast<const bf16x8*>(&As[buf][row*32 + ce]);
    }
    #pragma unroll
    for (int n=0;n<NF;n++){
      int row = wn*(NF*16) + n*16 + lr;
      bfr[n] = *reinterpret_cast<const bf16x8*>(&Bs[buf][row*32 + ce]);
    }
    #pragma unroll
    for (int m=0;m<MF;m++)
      #pragma unroll
      for (int n=0;n<NF;n++)
        acc[m][n] = __builtin_amdgcn_mfma_f32_16x16x32_bf16(af[m], bfr[n], acc[m][n], 0,0,0);
  };

  const int nt = K >> 5;           // >= 4 for all our shapes
  stage(0); stage(1); stage(2);
  for (int t=0; t<nt-2; ++t){
    asm volatile("s_waitcnt vmcnt(8)" ::: "memory");
    asm volatile("s_barrier" ::: "memory");
    if (t+3 < nt) stage(t+3);
    comp(t);
  }
  asm volatile("s_waitcnt vmcnt(4)" ::: "memory");
  asm volatile("s_barrier" ::: "memory");
  comp(nt-2);
  asm volatile("s_waitcnt vmcnt(0)" ::: "memory");
  asm volatile("s_barrier" ::: "memory");
  comp(nt-1);

  #pragma unroll
  for (int m=0;m<MF;m++){
    int row = m0 + wm*(MF*16) + m*16 + lq*4;
    #pragma unroll
    for (int n=0;n<NF;n++){
      int col = n0 + wn*(NF*16) + n*16 + lr;
      if (!GUARD || col < N){
        #pragma unroll
        for (int j=0;j<4;j++){
          float v = acc[m][n][j];
          size_t r = (size_t)(row+j);
          if (MODE == 0)      ((float*)Cp)[r*ldc + col] = v;
          else if (MODE == 1) ((u16*)Cp)[r*ldc + col] = f2bf(v);
          else {
            u16 bv = f2bf(v);
            if (col < 2048)      zb[r*2048 + col] = bv;
            else if (col < 4352) xb[r*2304 + (col-2048)] = bv;
            else                 db_[r*64 + (col-4352)] = bv;
          }
        }
      }
    }
  }
}

// ---------------- old 128-tile GEMM (kept for the skinny Dscal matmul) ------
template<int GUARD, int MODE>
__global__ __launch_bounds__(256) void gemm_bt(
    const u16* __restrict__ A, int lda,
    const u16* __restrict__ Bt, int ldb,
    void* __restrict__ Cp, int ldc,
    int M, int N, int K,
    u16* __restrict__ zb, u16* __restrict__ xb, u16* __restrict__ db_)
{
  __shared__ __align__(16) u16 As[128*64];
  __shared__ __align__(16) u16 Bs[128*64];
  const int tid  = threadIdx.x;
  const int wid  = tid >> 6;
  const int lane = tid & 63;
  const int nwg = gridDim.x * gridDim.y;
  const int bid = blockIdx.y * gridDim.x + blockIdx.x;
  const int q8  = nwg >> 3;
  const int swz = (nwg >= 8) ? ((bid & 7)*q8 + (bid >> 3)) : bid;
  const int m0 = (swz / gridDim.x) * 128;
  const int n0 = (swz % gridDim.x) * 128;
  const int wr = wid >> 1, wc = wid & 1;
  const int lq = lane >> 4, lr = lane & 15;

  f32x4 acc[4][4];
  #pragma unroll
  for (int m=0;m<4;m++)
    #pragma unroll
    for (int n=0;n<4;n++) acc[m][n] = (f32x4){0.f,0.f,0.f,0.f};

  const int srow = wid*32 + (lane>>3);
  const int scol = (lane&7)*8;

  for (int k0=0; k0<K; k0+=64){
    #pragma unroll
    for (int i=0;i<4;i++){
      const u16* ga = A + (size_t)(m0 + srow + i*8)*lda + k0 + scol;
      __builtin_amdgcn_global_load_lds(
        (const __attribute__((address_space(1))) void*)ga,
        (__attribute__((address_space(3))) void*)&As[(wid*32+i*8)*64], 16, 0, 0);
    }
    #pragma unroll
    for (int i=0;i<4;i++){
      int gn = n0 + srow + i*8;
      if (GUARD) gn = (gn < N) ? gn : (N-1);
      const u16* gb = Bt + (size_t)gn*ldb + k0 + scol;
      __builtin_amdgcn_global_load_lds(
        (const __attribute__((address_space(1))) void*)gb,
        (__attribute__((address_space(3))) void*)&Bs[(wid*32+i*8)*64], 16, 0, 0);
    }
    __syncthreads();
    #pragma unroll
    for (int kk=0;kk<2;kk++){
      bf16x8 af[4], bfr[4];
      #pragma unroll
      for (int m=0;m<4;m++)
        af[m] = *reinterpret_cast<const bf16x8*>(&As[(wr*64 + m*16 + lr)*64 + kk*32 + lq*8]);
      #pragma unroll
      for (int n=0;n<4;n++)
        bfr[n] = *reinterpret_cast<const bf16x8*>(&Bs[(wc*64 + n*16 + lr)*64 + kk*32 + lq*8]);
      #pragma unroll
      for (int m=0;m<4;m++)
        #pragma unroll
        for (int n=0;n<4;n++)
          acc[m][n] = __builtin_amdgcn_mfma_f32_16x16x32_bf16(af[m], bfr[n], acc[m][n], 0,0,0);
    }
    __syncthreads();
  }

  #pragma unroll
  for (int m=0;m<4;m++){
    int row = m0 + wr*64 + m*16 + lq*4;
    #pragma unroll
    for (int n=0;n<4;n++){
      int col = n0 + wc*64 + n*16 + lr;
      if (!GUARD || col < N){
        #pragma unroll
        for (int j=0;j<4;j++){
          float v = acc[m][n][j];
          size_t r = (size_t)(row+j);
          if (MODE == 0)      ((float*)Cp)[r*ldc + col] = v;
          else if (MODE == 1) ((u16*)Cp)[r*ldc + col] = f2bf(v);
          else {
            u16 bv = f2bf(v);
            if (col < 2048)      zb[r*2048 + col] = bv;
            else if (col < 4352) xb[r*2304 + (col-2048)] = bv;
            else                 db_[r*64 + (col-4352)] = bv;
          }
        }
      }
    }
  }
}

// ---------------- depthwise conv7 (SAME) + bias + SiLU -> bf16 ----------------
__global__ __launch_bounds__(256) void conv_silu(
    const u16* __restrict__ xbc, const u16* __restrict__ wtb,
    const float* __restrict__ bias, u16* __restrict__ xc)
{
  const int bid = blockIdx.x;
  const int sb  = (bid & 7)*1152 + (bid >> 3);
  const int idx = sb*256 + threadIdx.x;       // < 8192*288
  const int g   = idx % 288;
  const int row = idx / 288;
  const int l = row & 4095;
  const int c = g*8;
  float a[8];
  float4 b0 = *reinterpret_cast<const float4*>(&bias[c]);
  float4 b1 = *reinterpret_cast<const float4*>(&bias[c+4]);
  a[0]=b0.x; a[1]=b0.y; a[2]=b0.z; a[3]=b0.w;
  a[4]=b1.x; a[5]=b1.y; a[6]=b1.z; a[7]=b1.w;
  #pragma unroll
  for (int t=0;t<7;t++){
    int ls = l + t - 3;
    if (ls >= 0 && ls < 4096){
      bf16x8 v  = *reinterpret_cast<const bf16x8*>(&xbc[(size_t)(row + t - 3)*2304 + c]);
      bf16x8 wv = *reinterpret_cast<const bf16x8*>(&wtb[t*2304 + c]);
      #pragma unroll
      for (int j=0;j<8;j++) a[j] += bf2f((u16)v[j]) * bf2f((u16)wv[j]);
    }
  }
  bf16x8 o;
  #pragma unroll
  for (int j=0;j<8;j++){
    float s = a[j]/(1.f+__expf(-a[j]));
    o[j] = (short)f2bf(s);
  }
  *reinterpret_cast<bf16x8*>(&xc[(size_t)row*2304 + c]) = o;
}

// ================= chunked SSD scan (Q=64) =================
__global__ __launch_bounds__(256) void ssd_chunk(
    const u16* __restrict__ xc, const u16* __restrict__ dtb,
    const float* __restrict__ dt_bias, const float* __restrict__ A_log,
    u16* __restrict__ yP, u16* __restrict__ dB, float* __restrict__ csum, int dir)
{
  const int c  = blockIdx.x & 63;
  const int th = blockIdx.x >> 6;
  const int h  = th & 31;
  const int b  = th >> 5;
  const int tid = threadIdx.x;
  const int wid = tid >> 6;
  const int lane = tid & 63;
  const int lq = lane >> 4, lr = lane & 15;

  __shared__ __align__(16) u16 Cs[64*64];
  __shared__ __align__(16) u16 Bls[64*64];
  __shared__ __align__(16) u16 Xt[64*64];
  __shared__ __align__(16) u16 Gm[64*64];
  __shared__ __align__(16) u16 Bwt[64*64];
  __shared__ float cum[64], dtl[64];

  const float Ah = -__expf(A_log[h]);

  for (int e = tid; e < 512; e += 256){
    int i = e >> 3, g = e & 7;
    int l = dir ? (4095 - (c*64+i)) : (c*64+i);
    size_t rb = (size_t)(b*4096 + l)*2304;
    *reinterpret_cast<bf16x8*>(&Bls[i*64+g*8]) =
        *reinterpret_cast<const bf16x8*>(&xc[rb + 2048 + dir*128 + g*8]);
    *reinterpret_cast<bf16x8*>(&Cs[i*64+g*8]) =
        *reinterpret_cast<const bf16x8*>(&xc[rb + 2112 + dir*128 + g*8]);
  }
  for (int e = tid; e < 512; e += 256){
    int i = e & 63, g = e >> 6;
    int l = dir ? (4095 - (c*64+i)) : (c*64+i);
    bf16x8 xv = *reinterpret_cast<const bf16x8*>(&xc[(size_t)(b*4096+l)*2304 + (size_t)h*64 + g*8]);
    #pragma unroll
    for (int j=0;j<8;j++) Xt[(g*8+j)*64 + i] = (u16)xv[j];
  }
  if (tid < 64){
    int i = tid;
    int l = dir ? (4095 - (c*64+i)) : (c*64+i);
    float raw = bf2f(dtb[(size_t)(b*4096+l)*64 + dir*32 + h]) + dt_bias[h];
    float dte = (raw > 20.f) ? raw : log1pf(__expf(raw));
    dtl[i] = dte;
    float s = dte;
    #pragma unroll
    for (int off=1; off<64; off<<=1){
      float o = __shfl_up(s, off, 64);
      if (i >= off) s += o;
    }
    cum[i] = s;
    if (i == 63) csum[blockIdx.x] = s;
  }
  __syncthreads();

  f32x4 g4[4];
  #pragma unroll
  for (int n=0;n<4;n++) g4[n] = (f32x4){0.f,0.f,0.f,0.f};
  #pragma unroll
  for (int kk=0;kk<2;kk++){
    bf16x8 ca = *reinterpret_cast<const bf16x8*>(&Cs[(wid*16+lr)*64 + kk*32 + lq*8]);
    #pragma unroll
    for (int n=0;n<4;n++){
      bf16x8 bb = *reinterpret_cast<const bf16x8*>(&Bls[(n*16+lr)*64 + kk*32 + lq*8]);
      g4[n] = __builtin_amdgcn_mfma_f32_16x16x32_bf16(ca, bb, g4[n], 0,0,0);
    }
  }
  #pragma unroll
  for (int n=0;n<4;n++){
    #pragma unroll
    for (int r=0;r<4;r++){
      int gi = wid*16 + lq*4 + r;
      int gj = n*16 + lr;
      float wgt = (gj <= gi) ? __expf(Ah*(cum[gi]-cum[gj]))*dtl[gj] : 0.f;
      Gm[gi*64+gj] = f2bf(g4[n][r]*wgt);
    }
  }
  float ctot = cum[63];
  for (int e = tid; e < 512; e += 256){
    int j = e & 63, g = e >> 6;
    float wj = __expf(Ah*(ctot - cum[j])) * dtl[j];
    bf16x8 bv = *reinterpret_cast<const bf16x8*>(&Bls[j*64 + g*8]);
    #pragma unroll
    for (int nn=0;nn<8;nn++) Bwt[(g*8+nn)*64 + j] = f2bf(wj * bf2f((u16)bv[nn]));
  }
  __syncthreads();

  f32x4 yi[4], db4[4];
  #pragma unroll
  for (int n=0;n<4;n++){ yi[n] = (f32x4){0.f,0.f,0.f,0.f}; db4[n] = (f32x4){0.f,0.f,0.f,0.f}; }
  #pragma unroll
  for (int kk=0;kk<2;kk++){
    bf16x8 ga = *reinterpret_cast<const bf16x8*>(&Gm[(wid*16+lr)*64 + kk*32 + lq*8]);
    bf16x8 xa = *reinterpret_cast<const bf16x8*>(&Xt[(wid*16+lr)*64 + kk*32 + lq*8]);
    #pragma unroll
    for (int n=0;n<4;n++){
      bf16x8 xb = *reinterpret_cast<const bf16x8*>(&Xt[(n*16+lr)*64 + kk*32 + lq*8]);
      yi[n] = __builtin_amdgcn_mfma_f32_16x16x32_bf16(ga, xb, yi[n], 0,0,0);
      bf16x8 wb = *reinterpret_cast<const bf16x8*>(&Bwt[(n*16+lr)*64 + kk*32 + lq*8]);
      db4[n] = __builtin_amdgcn_mfma_f32_16x16x32_bf16(xa, wb, db4[n], 0,0,0);
    }
  }
  #pragma unroll
  for (int n=0;n<4;n++){
    #pragma unroll
    for (int r=0;r<4;r++){
      int i = wid*16 + lq*4 + r;
      yP[(size_t)(b*4096 + c*64 + i)*2048 + (size_t)h*64 + n*16 + lr] = f2bf(yi[n][r]);
    }
  }
  u16* dst = dB + (size_t)blockIdx.x*4096;
  #pragma unroll
  for (int n=0;n<4;n++){
    #pragma unroll
    for (int r=0;r<4;r++){
      int p = wid*16 + lq*4 + r;
      dst[p*64 + n*16 + lr] = f2bf(db4[n][r]);
    }
  }
}

// Pass B1: sequential h-chain over chunks, slot-shift in-place.
__global__ __launch_bounds__(256) void ssd_state(
    u16* __restrict__ dB, const float* __restrict__ csum,
    const float* __restrict__ A_log)
{
  const int q = blockIdx.x & 3;
  const int task = blockIdx.x >> 2;
  const int h = task & 31;
  const float Ah = -__expf(A_log[h]);
  const int p  = q*16 + (threadIdx.x >> 4);
  const int nb = (threadIdx.x & 15) * 4;
  float h0=0.f, h1=0.f, h2=0.f, h3=0.f;
  for (int c=0; c<63; ++c){
    float P = __expf(Ah * csum[task*64 + c]);
    u16* ptr = dB + ((size_t)(task*64 + c))*4096 + p*64 + nb;
    ushort4 dv = *reinterpret_cast<const ushort4*>(ptr);
    h0 = P*h0 + bf2f(dv.x);
    h1 = P*h1 + bf2f(dv.y);
    h2 = P*h2 + bf2f(dv.z);
    h3 = P*h3 + bf2f(dv.w);
    *reinterpret_cast<ushort4*>(ptr) = make_ushort4(f2bf(h0),f2bf(h1),f2bf(h2),f2bf(h3));
  }
}

// Pass B2: y += cd[i] * (C @ h_in^T). chunk 0 skipped.
__global__ __launch_bounds__(256) void ssd_yinter(
    const u16* __restrict__ xc, const u16* __restrict__ dtb,
    const float* __restrict__ dt_bias, const float* __restrict__ A_log,
    const u16* __restrict__ dB, u16* __restrict__ yP, int dir)
{
  const int c  = blockIdx.x & 63;
  if (c == 0) return;
  const int th = blockIdx.x >> 6;
  const int h  = th & 31;
  const int b  = th >> 5;
  const int tid = threadIdx.x;
  const int wid = tid >> 6;
  const int lane = tid & 63;
  const int lq = lane >> 4, lr = lane & 15;

  __shared__ __align__(16) u16 Cs[64*64];
  __shared__ __align__(16) u16 Hs[64*64];
  __shared__ float cum[64];

  const float Ah = -__expf(A_log[h]);

  for (int e = tid; e < 512; e += 256){
    int i = e >> 3, g = e & 7;
    int l = dir ? (4095 - (c*64+i)) : (c*64+i);
    *reinterpret_cast<bf16x8*>(&Cs[i*64+g*8]) =
        *reinterpret_cast<const bf16x8*>(&xc[(size_t)(b*4096+l)*2304 + 2112 + dir*128 + g*8]);
    *reinterpret_cast<bf16x8*>(&Hs[e*8]) =
        *reinterpret_cast<const bf16x8*>(&dB[(size_t)(blockIdx.x-1)*4096 + e*8]);
  }
  if (tid < 64){
    int i = tid;
    int l = dir ? (4095 - (c*64+i)) : (c*64+i);
    float raw = bf2f(dtb[(size_t)(b*4096+l)*64 + dir*32 + h]) + dt_bias[h];
    float dte = (raw > 20.f) ? raw : log1pf(__expf(raw));
    float s = dte;
    #pragma unroll
    for (int off=1; off<64; off<<=1){
      float o = __shfl_up(s, off, 64);
      if (i >= off) s += o;
    }
    cum[i] = s;
  }
  __syncthreads();

  f32x4 acc[4];
  #pragma unroll
  for (int n=0;n<4;n++) acc[n] = (f32x4){0.f,0.f,0.f,0.f};
  #pragma unroll
  for (int kk=0;kk<2;kk++){
    bf16x8 ca = *reinterpret_cast<const bf16x8*>(&Cs[(wid*16+lr)*64 + kk*32 + lq*8]);
    #pragma unroll
    for (int n=0;n<4;n++){
      bf16x8 hb = *reinterpret_cast<const bf16x8*>(&Hs[(n*16+lr)*64 + kk*32 + lq*8]);
      acc[n] = __builtin_amdgcn_mfma_f32_16x16x32_bf16(ca, hb, acc[n], 0,0,0);
    }
  }
  #pragma unroll
  for (int n=0;n<4;n++){
    #pragma unroll
    for (int r=0;r<4;r++){
      int i = wid*16 + lq*4 + r;
      float cd = __expf(Ah*cum[i]);
      size_t a = (size_t)(b*4096 + c*64 + i)*2048 + (size_t)h*64 + n*16 + lr;
      yP[a] = f2bf(bf2f(yP[a]) + cd*acc[n][r]);
    }
  }
}

// ---------------- fuse: y-combine(shift/flip) + D*x + RMSNorm + SiLU(z) ------
__global__ __launch_bounds__(256) void fuse_rms(
    const u16* __restrict__ ypF, const u16* __restrict__ ypB,
    const u16* __restrict__ xc, const u16* __restrict__ zbuf,
    u16* __restrict__ un,
    const float* __restrict__ Dscal, const float* __restrict__ D_b,
    const float* __restrict__ rms_w)
{
  const int row = blockIdx.x;
  const int l = row & 4095;
  const int tid = threadIdx.x;
  const int c = tid*8;
  const int hh = tid >> 3;
  float v[8]; float ss = 0.f;
  const bool hasF = (l >= 1);
  const bool hasB = (l <= 4094);
  bf16x8 yf, yb;
  if (hasF) yf = *reinterpret_cast<const bf16x8*>(&ypF[(size_t)(row-1)*2048 + c]);
  if (hasB) yb = *reinterpret_cast<const bf16x8*>(&ypB[(size_t)(row + 4094 - 2*l)*2048 + c]);
  bf16x8 xv = *reinterpret_cast<const bf16x8*>(&xc[(size_t)row*2304 + c]);
  const float dsc = Dscal[(size_t)row*32 + hh] + D_b[hh];
  #pragma unroll
  for (int i=0;i<8;i++){
    float y = hasF ? bf2f((u16)yf[i]) : 0.f;
    if (hasB) y += bf2f((u16)yb[i]);
    y += dsc * bf2f((u16)xv[i]);
    v[i] = y;
    ss += y*y;
  }
  #pragma unroll
  for (int o=1;o<64;o<<=1) ss += __shfl_xor(ss, o, 64);
  __shared__ float sred[4];
  if ((tid & 63) == 0) sred[tid>>6] = ss;
  __syncthreads();
  float rstd = rsqrtf((sred[0]+sred[1]+sred[2]+sred[3]) * (1.f/2048.f) + 1e-5f);
  bf16x8 zv = *reinterpret_cast<const bf16x8*>(&zbuf[(size_t)row*2048 + c]);
  bf16x8 o;
  #pragma unroll
  for (int i=0;i<8;i++){
    float z = bf2f((u16)zv[i]);
    float sz = z / (1.f + __expf(-z));
    o[i] = (short)f2bf(v[i]*rstd*rms_w[c+i]*sz);
  }
  *reinterpret_cast<bf16x8*>(&un[(size_t)row*2048 + c]) = o;
}

extern "C" void kernel_launch(void* const* d_in, const int* in_sizes, int n_in,
                              void* d_out, int out_size, void* d_ws, size_t ws_size,
                              hipStream_t stream)
{
  const float* u       = (const float*)d_in[0];
  const float* w_in    = (const float*)d_in[1];
  const float* conv_w  = (const float*)d_in[2];
  const float* conv_b  = (const float*)d_in[3];
  const float* dt_bias = (const float*)d_in[4];
  const float* A_log   = (const float*)d_in[5];
  const float* D_w     = (const float*)d_in[6];
  const float* D_b     = (const float*)d_in[7];
  const float* rms_w   = (const float*)d_in[8];
  const float* w_out   = (const float*)d_in[9];
  float* out = (float*)d_out;
  (void)in_sizes; (void)n_in; (void)out_size; (void)ws_size;

  char* ws = (char*)d_ws;
  u16*   zbuf = (u16*)(ws);                         // 8192x2048 bf16
  u16*   xbc  = (u16*)(ws + 33554432);              // 8192x2304 bf16 (dead after conv -> dB -> un)
  u16*   dtbuf= (u16*)(ws + 71303168);              // 8192x64  bf16
  u16*   xc   = (u16*)(ws + 72351744);              // 8192x2304 bf16
  u16*   ypF  = (u16*)(ws + 110100480);             // 8192x2048 bf16
  u16*   ypB  = (u16*)(ws + 143654912);             // 8192x2048 bf16
  float* Dsc  = (float*)(ws + 177209344);           // 8192x32 f32
  u16*   w2b  = (u16*)(ws + 178257920);             // 1024x2048 bf16
  u16*   dwb  = (u16*)(ws + 182452224);             // 32x2048 bf16
  float* csum = (float*)(ws + 182583296);           // 2 x 4096 f32
  u16*   wtb  = (u16*)(ws + 182616064);             // 7x2304 bf16
  // aliases
  u16*   ub   = ypF;
  u16*   w1b  = ypF + (size_t)8192*1024;
  u16*   dB   = xbc;
  u16*   un   = xbc;

  cvt_f32_bf16<<<8192,256,0,stream>>>(u,     ub,  8192*1024/4);
  cvt_f32_bf16<<<4416,256,0,stream>>>(w_in,  w1b, 4416*1024/4);
  cvt_f32_bf16<<<2048,256,0,stream>>>(w_out, w2b, 1024*2048/4);
  cvt_f32_bf16<<<64,  256,0,stream>>>(D_w,   dwb, 32*2048/4);
  conv_prep<<<63,256,0,stream>>>(conv_w, wtb);

  // zxBCdt = u @ in_proj_w^T  (split into zbuf / xbc / dtbuf)
  gemm_p<1,2,256,256,2,4><<<dim3(18,32),512,0,stream>>>(ub,1024, w1b,1024, nullptr,0,
                                                        8192,4416,1024, zbuf, xbc, dtbuf);
  // depthwise conv + silu -> xc
  conv_silu<<<9216,256,0,stream>>>(xbc, wtb, conv_b, xc);
  // Dscal = x_og @ D_w^T  (f32)
  gemm_bt<1,0><<<dim3(1,64),256,0,stream>>>(xc,2304, dwb,2048, Dsc,32,
                                            8192,32,2048, nullptr,nullptr,nullptr);
  // chunked SSD scan, per direction
  for (int dir=0; dir<2; ++dir){
    u16* yP = dir ? ypB : ypF;
    ssd_chunk <<<4096,256,0,stream>>>(xc, dtbuf, dt_bias, A_log, yP, dB, csum + dir*4096, dir);
    ssd_state <<<256, 256,0,stream>>>(dB, csum + dir*4096, A_log);
    ssd_yinter<<<4096,256,0,stream>>>(xc, dtbuf, dt_bias, A_log, dB, yP, dir);
  }
  // combine + D path + RMS + gate -> un
  fuse_rms<<<8192,256,0,stream>>>(ypF, ypB, xc, zbuf, un, Dsc, D_b, rms_w);
  // out = un @ outproj_w^T  (f32)
  gemm_p<0,0,128,128,2,2><<<dim3(8,64),256,0,stream>>>(un,2048, w2b,2048, out,1024,
                                                       8192,1024,2048, nullptr,nullptr,nullptr);
}

// Round 8
// 449.138 us; speedup vs baseline: 1.0653x; 1.0311x over previous
//
#include <hip/hip_runtime.h>

typedef unsigned short u16;
typedef __attribute__((ext_vector_type(8))) short bf16x8;
typedef __attribute__((ext_vector_type(4))) float f32x4;

__device__ __forceinline__ float bf2f(u16 u){
  union { unsigned int i; float f; } x; x.i = ((unsigned int)u) << 16; return x.f;
}
__device__ __forceinline__ u16 f2bf(float f){
  union { float f; unsigned int i; } x; x.f = f;
  unsigned int r = x.i + 0x7fffu + ((x.i >> 16) & 1u);
  return (u16)(r >> 16);
}

template<int N> __device__ __forceinline__ void waitcnt_vm(){
  if constexpr (N==0)       asm volatile("s_waitcnt vmcnt(0)" ::: "memory");
  else if constexpr (N==4)  asm volatile("s_waitcnt vmcnt(4)" ::: "memory");
  else if constexpr (N==6)  asm volatile("s_waitcnt vmcnt(6)" ::: "memory");
  else if constexpr (N==8)  asm volatile("s_waitcnt vmcnt(8)" ::: "memory");
  else if constexpr (N==12) asm volatile("s_waitcnt vmcnt(12)" ::: "memory");
}

// ---------------- f32 -> bf16 convert (vectorized) ----------------
__global__ __launch_bounds__(256) void cvt_f32_bf16(const float* __restrict__ in,
                                                    u16* __restrict__ out, int n4){
  int i = blockIdx.x*256 + threadIdx.x;
  if (i < n4){
    float4 v = reinterpret_cast<const float4*>(in)[i];
    ushort4 o = make_ushort4(f2bf(v.x), f2bf(v.y), f2bf(v.z), f2bf(v.w));
    reinterpret_cast<ushort4*>(out)[i] = o;
  }
}

// ---------------- conv weight transpose: w[2304][7] -> wtb[7][2304] bf16 -----
__global__ __launch_bounds__(256) void conv_prep(const float* __restrict__ w,
                                                 u16* __restrict__ wtb){
  int i = blockIdx.x*256 + threadIdx.x;
  if (i < 2304*7){
    int ch = i / 7, t = i % 7;
    wtb[t*2304 + ch] = f2bf(w[i]);
  }
}

// ====== counted-vmcnt pipelined bf16 MFMA GEMM, BK=32, 3 LDS bufs ===========
// SAFE ordering (r6-proven): waitcnt vmcnt(LPS) -> s_barrier -> stage(t+2)
// -> comp(t). Barrier guarantees all waves finished comp(t-1) (their ds_reads
// drained before MFMA issue), so stage(t+2)'s write to buf[(t-1)%3] is safe.
// vmcnt(LPS): retires stage(t) (FIFO) while stage(t+1) stays in flight.
// LDS <= 72KB -> 2-3 blocks/CU for cross-block TLP (m114). T5 setprio.
// MODE 0: f32 out. MODE 2: split z/xbc/dt (gemm1).
template<int GUARD, int MODE, int BM, int BN, int NM, int NN>
__global__ __launch_bounds__(256, 2) void gemm_p(
    const u16* __restrict__ A, int lda,
    const u16* __restrict__ Bt, int ldb,
    void* __restrict__ Cp, int ldc,
    int M, int N, int K,
    u16* __restrict__ zb, u16* __restrict__ xb, u16* __restrict__ db_)
{
  constexpr int T   = 64*NM*NN;
  constexpr int MF  = BM/NM/16;
  constexpr int NF  = BN/NN/16;
  constexpr int LPS = (BM+BN)*4/T;       // gload_lds per thread per stage
  __shared__ __align__(16) u16 As[3][BM*32];
  __shared__ __align__(16) u16 Bs[3][BN*32];
  const int tid  = threadIdx.x;
  const int wid  = tid >> 6;
  const int lane = tid & 63;
  // XCD-chunked bijective swizzle (grids are multiples of 8)
  const int nwg = gridDim.x * gridDim.y;
  const int bid = blockIdx.y * gridDim.x + blockIdx.x;
  const int q8  = nwg >> 3;
  const int swz = (bid & 7)*q8 + (bid >> 3);
  const int m0 = (swz / gridDim.x) * BM;
  const int n0 = (swz % gridDim.x) * BN;
  const int wm = wid / NN;
  const int wn = wid % NN;
  const int lq = lane >> 4, lr = lane & 15;
  // read-side XOR (must match stage()'s source-column XOR)
  const int ce = (lq ^ ((lr&3) ^ ((lr>>2)&3))) * 8;

  f32x4 acc[MF][NF];
  #pragma unroll
  for (int m=0;m<MF;m++)
    #pragma unroll
    for (int n=0;n<NF;n++) acc[m][n] = (f32x4){0.f,0.f,0.f,0.f};

  auto stage = [&](int t){
    const int buf = t % 3;
    const int k0  = t << 5;
    #pragma unroll
    for (int i=0;i<(BM*4)/T;i++){
      int slot = i*T + tid;
      int row = slot >> 2, cg = slot & 3;
      int sc = cg ^ ((row&3) ^ ((row>>2)&3));
      const u16* ga = A + (size_t)(m0 + row)*lda + k0 + sc*8;
      __builtin_amdgcn_global_load_lds(
        (const __attribute__((address_space(1))) void*)ga,
        (__attribute__((address_space(3))) void*)&As[buf][slot*8], 16, 0, 0);
    }
    #pragma unroll
    for (int i=0;i<(BN*4)/T;i++){
      int slot = i*T + tid;
      int row = slot >> 2, cg = slot & 3;
      int gn = n0 + row;
      if (GUARD) gn = (gn < N) ? gn : (N-1);
      int sc = cg ^ ((row&3) ^ ((row>>2)&3));
      const u16* gb = Bt + (size_t)gn*ldb + k0 + sc*8;
      __builtin_amdgcn_global_load_lds(
        (const __attribute__((address_space(1))) void*)gb,
        (__attribute__((address_space(3))) void*)&Bs[buf][slot*8], 16, 0, 0);
    }
  };

  auto comp = [&](int t){
    const int buf = t % 3;
    bf16x8 af[MF], bfr[NF];
    #pragma unroll
    for (int m=0;m<MF;m++){
      int row = wm*(MF*16) + m*16 + lr;
      af[m] = *reinterpret_cast<const bf16x8*>(&As[buf][row*32 + ce]);
    }
    #pragma unroll
    for (int n=0;n<NF;n++){
      int row = wn*(NF*16) + n*16 + lr;
      bfr[n] = *reinterpret_cast<const bf16x8*>(&Bs[buf][row*32 + ce]);
    }
    __builtin_amdgcn_s_setprio(1);
    #pragma unroll
    for (int m=0;m<MF;m++)
      #pragma unroll
      for (int n=0;n<NF;n++)
        acc[m][n] = __builtin_amdgcn_mfma_f32_16x16x32_bf16(af[m], bfr[n], acc[m][n], 0,0,0);
    __builtin_amdgcn_s_setprio(0);
  };

  const int nt = K >> 5;                 // >= 4 for all our shapes
  stage(0); stage(1);
  for (int t=0; t<nt; ++t){
    if (t+1 < nt) waitcnt_vm<LPS>();
    else          waitcnt_vm<0>();
    asm volatile("s_barrier" ::: "memory");
    if (t+2 < nt) stage(t+2);
    comp(t);
  }

  #pragma unroll
  for (int m=0;m<MF;m++){
    int row = m0 + wm*(MF*16) + m*16 + lq*4;
    #pragma unroll
    for (int n=0;n<NF;n++){
      int col = n0 + wn*(NF*16) + n*16 + lr;
      if (!GUARD || col < N){
        #pragma unroll
        for (int j=0;j<4;j++){
          float v = acc[m][n][j];
          size_t r = (size_t)(row+j);
          if (MODE == 0)      ((float*)Cp)[r*ldc + col] = v;
          else if (MODE == 1) ((u16*)Cp)[r*ldc + col] = f2bf(v);
          else {
            u16 bv = f2bf(v);
            if (col < 2048)      zb[r*2048 + col] = bv;
            else if (col < 4352) xb[r*2304 + (col-2048)] = bv;
            else                 db_[r*64 + (col-4352)] = bv;
          }
        }
      }
    }
  }
}

// ---------------- old 128-tile GEMM (kept for the skinny Dscal matmul) ------
template<int GUARD, int MODE>
__global__ __launch_bounds__(256) void gemm_bt(
    const u16* __restrict__ A, int lda,
    const u16* __restrict__ Bt, int ldb,
    void* __restrict__ Cp, int ldc,
    int M, int N, int K,
    u16* __restrict__ zb, u16* __restrict__ xb, u16* __restrict__ db_)
{
  __shared__ __align__(16) u16 As[128*64];
  __shared__ __align__(16) u16 Bs[128*64];
  const int tid  = threadIdx.x;
  const int wid  = tid >> 6;
  const int lane = tid & 63;
  const int nwg = gridDim.x * gridDim.y;
  const int bid = blockIdx.y * gridDim.x + blockIdx.x;
  const int q8  = nwg >> 3;
  const int swz = (nwg >= 8) ? ((bid & 7)*q8 + (bid >> 3)) : bid;
  const int m0 = (swz / gridDim.x) * 128;
  const int n0 = (swz % gridDim.x) * 128;
  const int wr = wid >> 1, wc = wid & 1;
  const int lq = lane >> 4, lr = lane & 15;

  f32x4 acc[4][4];
  #pragma unroll
  for (int m=0;m<4;m++)
    #pragma unroll
    for (int n=0;n<4;n++) acc[m][n] = (f32x4){0.f,0.f,0.f,0.f};

  const int srow = wid*32 + (lane>>3);
  const int scol = (lane&7)*8;

  for (int k0=0; k0<K; k0+=64){
    #pragma unroll
    for (int i=0;i<4;i++){
      const u16* ga = A + (size_t)(m0 + srow + i*8)*lda + k0 + scol;
      __builtin_amdgcn_global_load_lds(
        (const __attribute__((address_space(1))) void*)ga,
        (__attribute__((address_space(3))) void*)&As[(wid*32+i*8)*64], 16, 0, 0);
    }
    #pragma unroll
    for (int i=0;i<4;i++){
      int gn = n0 + srow + i*8;
      if (GUARD) gn = (gn < N) ? gn : (N-1);
      const u16* gb = Bt + (size_t)gn*ldb + k0 + scol;
      __builtin_amdgcn_global_load_lds(
        (const __attribute__((address_space(1))) void*)gb,
        (__attribute__((address_space(3))) void*)&Bs[(wid*32+i*8)*64], 16, 0, 0);
    }
    __syncthreads();
    #pragma unroll
    for (int kk=0;kk<2;kk++){
      bf16x8 af[4], bfr[4];
      #pragma unroll
      for (int m=0;m<4;m++)
        af[m] = *reinterpret_cast<const bf16x8*>(&As[(wr*64 + m*16 + lr)*64 + kk*32 + lq*8]);
      #pragma unroll
      for (int n=0;n<4;n++)
        bfr[n] = *reinterpret_cast<const bf16x8*>(&Bs[(wc*64 + n*16 + lr)*64 + kk*32 + lq*8]);
      #pragma unroll
      for (int m=0;m<4;m++)
        #pragma unroll
        for (int n=0;n<4;n++)
          acc[m][n] = __builtin_amdgcn_mfma_f32_16x16x32_bf16(af[m], bfr[n], acc[m][n], 0,0,0);
    }
    __syncthreads();
  }

  #pragma unroll
  for (int m=0;m<4;m++){
    int row = m0 + wr*64 + m*16 + lq*4;
    #pragma unroll
    for (int n=0;n<4;n++){
      int col = n0 + wc*64 + n*16 + lr;
      if (!GUARD || col < N){
        #pragma unroll
        for (int j=0;j<4;j++){
          float v = acc[m][n][j];
          size_t r = (size_t)(row+j);
          if (MODE == 0)      ((float*)Cp)[r*ldc + col] = v;
          else if (MODE == 1) ((u16*)Cp)[r*ldc + col] = f2bf(v);
          else {
            u16 bv = f2bf(v);
            if (col < 2048)      zb[r*2048 + col] = bv;
            else if (col < 4352) xb[r*2304 + (col-2048)] = bv;
            else                 db_[r*64 + (col-4352)] = bv;
          }
        }
      }
    }
  }
}

// ---------------- depthwise conv7 (SAME) + bias + SiLU -> bf16 ----------------
__global__ __launch_bounds__(256) void conv_silu(
    const u16* __restrict__ xbc, const u16* __restrict__ wtb,
    const float* __restrict__ bias, u16* __restrict__ xc)
{
  const int bid = blockIdx.x;
  const int sb  = (bid & 7)*1152 + (bid >> 3);
  const int idx = sb*256 + threadIdx.x;       // < 8192*288
  const int g   = idx % 288;
  const int row = idx / 288;
  const int l = row & 4095;
  const int c = g*8;
  float a[8];
  float4 b0 = *reinterpret_cast<const float4*>(&bias[c]);
  float4 b1 = *reinterpret_cast<const float4*>(&bias[c+4]);
  a[0]=b0.x; a[1]=b0.y; a[2]=b0.z; a[3]=b0.w;
  a[4]=b1.x; a[5]=b1.y; a[6]=b1.z; a[7]=b1.w;
  #pragma unroll
  for (int t=0;t<7;t++){
    int ls = l + t - 3;
    if (ls >= 0 && ls < 4096){
      bf16x8 v  = *reinterpret_cast<const bf16x8*>(&xbc[(size_t)(row + t - 3)*2304 + c]);
      bf16x8 wv = *reinterpret_cast<const bf16x8*>(&wtb[t*2304 + c]);
      #pragma unroll
      for (int j=0;j<8;j++) a[j] += bf2f((u16)v[j]) * bf2f((u16)wv[j]);
    }
  }
  bf16x8 o;
  #pragma unroll
  for (int j=0;j<8;j++){
    float s = a[j]/(1.f+__expf(-a[j]));
    o[j] = (short)f2bf(s);
  }
  *reinterpret_cast<bf16x8*>(&xc[(size_t)row*2304 + c]) = o;
}

// ================= chunked SSD scan (Q=64) =================
__global__ __launch_bounds__(256) void ssd_chunk(
    const u16* __restrict__ xc, const u16* __restrict__ dtb,
    const float* __restrict__ dt_bias, const float* __restrict__ A_log,
    u16* __restrict__ yP, u16* __restrict__ dB, float* __restrict__ csum, int dir)
{
  const int c  = blockIdx.x & 63;
  const int th = blockIdx.x >> 6;
  const int h  = th & 31;
  const int b  = th >> 5;
  const int tid = threadIdx.x;
  const int wid = tid >> 6;
  const int lane = tid & 63;
  const int lq = lane >> 4, lr = lane & 15;

  __shared__ __align__(16) u16 Cs[64*64];
  __shared__ __align__(16) u16 Bls[64*64];
  __shared__ __align__(16) u16 Xt[64*64];
  __shared__ __align__(16) u16 Gm[64*64];
  __shared__ __align__(16) u16 Bwt[64*64];
  __shared__ float cum[64], dtl[64];

  const float Ah = -__expf(A_log[h]);

  for (int e = tid; e < 512; e += 256){
    int i = e >> 3, g = e & 7;
    int l = dir ? (4095 - (c*64+i)) : (c*64+i);
    size_t rb = (size_t)(b*4096 + l)*2304;
    *reinterpret_cast<bf16x8*>(&Bls[i*64+g*8]) =
        *reinterpret_cast<const bf16x8*>(&xc[rb + 2048 + dir*128 + g*8]);
    *reinterpret_cast<bf16x8*>(&Cs[i*64+g*8]) =
        *reinterpret_cast<const bf16x8*>(&xc[rb + 2112 + dir*128 + g*8]);
  }
  for (int e = tid; e < 512; e += 256){
    int i = e & 63, g = e >> 6;
    int l = dir ? (4095 - (c*64+i)) : (c*64+i);
    bf16x8 xv = *reinterpret_cast<const bf16x8*>(&xc[(size_t)(b*4096+l)*2304 + (size_t)h*64 + g*8]);
    #pragma unroll
    for (int j=0;j<8;j++) Xt[(g*8+j)*64 + i] = (u16)xv[j];
  }
  if (tid < 64){
    int i = tid;
    int l = dir ? (4095 - (c*64+i)) : (c*64+i);
    float raw = bf2f(dtb[(size_t)(b*4096+l)*64 + dir*32 + h]) + dt_bias[h];
    float dte = (raw > 20.f) ? raw : log1pf(__expf(raw));
    dtl[i] = dte;
    float s = dte;
    #pragma unroll
    for (int off=1; off<64; off<<=1){
      float o = __shfl_up(s, off, 64);
      if (i >= off) s += o;
    }
    cum[i] = s;
    if (i == 63) csum[blockIdx.x] = s;
  }
  __syncthreads();

  f32x4 g4[4];
  #pragma unroll
  for (int n=0;n<4;n++) g4[n] = (f32x4){0.f,0.f,0.f,0.f};
  #pragma unroll
  for (int kk=0;kk<2;kk++){
    bf16x8 ca = *reinterpret_cast<const bf16x8*>(&Cs[(wid*16+lr)*64 + kk*32 + lq*8]);
    #pragma unroll
    for (int n=0;n<4;n++){
      bf16x8 bb = *reinterpret_cast<const bf16x8*>(&Bls[(n*16+lr)*64 + kk*32 + lq*8]);
      g4[n] = __builtin_amdgcn_mfma_f32_16x16x32_bf16(ca, bb, g4[n], 0,0,0);
    }
  }
  #pragma unroll
  for (int n=0;n<4;n++){
    #pragma unroll
    for (int r=0;r<4;r++){
      int gi = wid*16 + lq*4 + r;
      int gj = n*16 + lr;
      float wgt = (gj <= gi) ? __expf(Ah*(cum[gi]-cum[gj]))*dtl[gj] : 0.f;
      Gm[gi*64+gj] = f2bf(g4[n][r]*wgt);
    }
  }
  float ctot = cum[63];
  for (int e = tid; e < 512; e += 256){
    int j = e & 63, g = e >> 6;
    float wj = __expf(Ah*(ctot - cum[j])) * dtl[j];
    bf16x8 bv = *reinterpret_cast<const bf16x8*>(&Bls[j*64 + g*8]);
    #pragma unroll
    for (int nn=0;nn<8;nn++) Bwt[(g*8+nn)*64 + j] = f2bf(wj * bf2f((u16)bv[nn]));
  }
  __syncthreads();

  f32x4 yi[4], db4[4];
  #pragma unroll
  for (int n=0;n<4;n++){ yi[n] = (f32x4){0.f,0.f,0.f,0.f}; db4[n] = (f32x4){0.f,0.f,0.f,0.f}; }
  #pragma unroll
  for (int kk=0;kk<2;kk++){
    bf16x8 ga = *reinterpret_cast<const bf16x8*>(&Gm[(wid*16+lr)*64 + kk*32 + lq*8]);
    bf16x8 xa = *reinterpret_cast<const bf16x8*>(&Xt[(wid*16+lr)*64 + kk*32 + lq*8]);
    #pragma unroll
    for (int n=0;n<4;n++){
      bf16x8 xb = *reinterpret_cast<const bf16x8*>(&Xt[(n*16+lr)*64 + kk*32 + lq*8]);
      yi[n] = __builtin_amdgcn_mfma_f32_16x16x32_bf16(ga, xb, yi[n], 0,0,0);
      bf16x8 wb = *reinterpret_cast<const bf16x8*>(&Bwt[(n*16+lr)*64 + kk*32 + lq*8]);
      db4[n] = __builtin_amdgcn_mfma_f32_16x16x32_bf16(xa, wb, db4[n], 0,0,0);
    }
  }
  #pragma unroll
  for (int n=0;n<4;n++){
    #pragma unroll
    for (int r=0;r<4;r++){
      int i = wid*16 + lq*4 + r;
      yP[(size_t)(b*4096 + c*64 + i)*2048 + (size_t)h*64 + n*16 + lr] = f2bf(yi[n][r]);
    }
  }
  u16* dst = dB + (size_t)blockIdx.x*4096;
  #pragma unroll
  for (int n=0;n<4;n++){
    #pragma unroll
    for (int r=0;r<4;r++){
      int p = wid*16 + lq*4 + r;
      dst[p*64 + n*16 + lr] = f2bf(db4[n][r]);
    }
  }
}

// Pass B1: sequential h-chain over chunks, slot-shift in-place.
__global__ __launch_bounds__(256) void ssd_state(
    u16* __restrict__ dB, const float* __restrict__ csum,
    const float* __restrict__ A_log)
{
  const int q = blockIdx.x & 3;
  const int task = blockIdx.x >> 2;
  const int h = task & 31;
  const float Ah = -__expf(A_log[h]);
  const int p  = q*16 + (threadIdx.x >> 4);
  const int nb = (threadIdx.x & 15) * 4;
  float h0=0.f, h1=0.f, h2=0.f, h3=0.f;
  for (int c=0; c<63; ++c){
    float P = __expf(Ah * csum[task*64 + c]);
    u16* ptr = dB + ((size_t)(task*64 + c))*4096 + p*64 + nb;
    ushort4 dv = *reinterpret_cast<const ushort4*>(ptr);
    h0 = P*h0 + bf2f(dv.x);
    h1 = P*h1 + bf2f(dv.y);
    h2 = P*h2 + bf2f(dv.z);
    h3 = P*h3 + bf2f(dv.w);
    *reinterpret_cast<ushort4*>(ptr) = make_ushort4(f2bf(h0),f2bf(h1),f2bf(h2),f2bf(h3));
  }
}

// Pass B2: y += cd[i] * (C @ h_in^T). chunk 0 skipped.
__global__ __launch_bounds__(256) void ssd_yinter(
    const u16* __restrict__ xc, const u16* __restrict__ dtb,
    const float* __restrict__ dt_bias, const float* __restrict__ A_log,
    const u16* __restrict__ dB, u16* __restrict__ yP, int dir)
{
  const int c  = blockIdx.x & 63;
  if (c == 0) return;
  const int th = blockIdx.x >> 6;
  const int h  = th & 31;
  const int b  = th >> 5;
  const int tid = threadIdx.x;
  const int wid = tid >> 6;
  const int lane = tid & 63;
  const int lq = lane >> 4, lr = lane & 15;

  __shared__ __align__(16) u16 Cs[64*64];
  __shared__ __align__(16) u16 Hs[64*64];
  __shared__ float cum[64];

  const float Ah = -__expf(A_log[h]);

  for (int e = tid; e < 512; e += 256){
    int i = e >> 3, g = e & 7;
    int l = dir ? (4095 - (c*64+i)) : (c*64+i);
    *reinterpret_cast<bf16x8*>(&Cs[i*64+g*8]) =
        *reinterpret_cast<const bf16x8*>(&xc[(size_t)(b*4096+l)*2304 + 2112 + dir*128 + g*8]);
    *reinterpret_cast<bf16x8*>(&Hs[e*8]) =
        *reinterpret_cast<const bf16x8*>(&dB[(size_t)(blockIdx.x-1)*4096 + e*8]);
  }
  if (tid < 64){
    int i = tid;
    int l = dir ? (4095 - (c*64+i)) : (c*64+i);
    float raw = bf2f(dtb[(size_t)(b*4096+l)*64 + dir*32 + h]) + dt_bias[h];
    float dte = (raw > 20.f) ? raw : log1pf(__expf(raw));
    float s = dte;
    #pragma unroll
    for (int off=1; off<64; off<<=1){
      float o = __shfl_up(s, off, 64);
      if (i >= off) s += o;
    }
    cum[i] = s;
  }
  __syncthreads();

  f32x4 acc[4];
  #pragma unroll
  for (int n=0;n<4;n++) acc[n] = (f32x4){0.f,0.f,0.f,0.f};
  #pragma unroll
  for (int kk=0;kk<2;kk++){
    bf16x8 ca = *reinterpret_cast<const bf16x8*>(&Cs[(wid*16+lr)*64 + kk*32 + lq*8]);
    #pragma unroll
    for (int n=0;n<4;n++){
      bf16x8 hb = *reinterpret_cast<const bf16x8*>(&Hs[(n*16+lr)*64 + kk*32 + lq*8]);
      acc[n] = __builtin_amdgcn_mfma_f32_16x16x32_bf16(ca, hb, acc[n], 0,0,0);
    }
  }
  #pragma unroll
  for (int n=0;n<4;n++){
    #pragma unroll
    for (int r=0;r<4;r++){
      int i = wid*16 + lq*4 + r;
      float cd = __expf(Ah*cum[i]);
      size_t a = (size_t)(b*4096 + c*64 + i)*2048 + (size_t)h*64 + n*16 + lr;
      yP[a] = f2bf(bf2f(yP[a]) + cd*acc[n][r]);
    }
  }
}

// ---------------- fuse: y-combine(shift/flip) + D*x + RMSNorm + SiLU(z) ------
__global__ __launch_bounds__(256) void fuse_rms(
    const u16* __restrict__ ypF, const u16* __restrict__ ypB,
    const u16* __restrict__ xc, const u16* __restrict__ zbuf,
    u16* __restrict__ un,
    const float* __restrict__ Dscal, const float* __restrict__ D_b,
    const float* __restrict__ rms_w)
{
  const int row = blockIdx.x;
  const int l = row & 4095;
  const int tid = threadIdx.x;
  const int c = tid*8;
  const int hh = tid >> 3;
  float v[8]; float ss = 0.f;
  const bool hasF = (l >= 1);
  const bool hasB = (l <= 4094);
  bf16x8 yf, yb;
  if (hasF) yf = *reinterpret_cast<const bf16x8*>(&ypF[(size_t)(row-1)*2048 + c]);
  if (hasB) yb = *reinterpret_cast<const bf16x8*>(&ypB[(size_t)(row + 4094 - 2*l)*2048 + c]);
  bf16x8 xv = *reinterpret_cast<const bf16x8*>(&xc[(size_t)row*2304 + c]);
  const float dsc = Dscal[(size_t)row*32 + hh] + D_b[hh];
  #pragma unroll
  for (int i=0;i<8;i++){
    float y = hasF ? bf2f((u16)yf[i]) : 0.f;
    if (hasB) y += bf2f((u16)yb[i]);
    y += dsc * bf2f((u16)xv[i]);
    v[i] = y;
    ss += y*y;
  }
  #pragma unroll
  for (int o=1;o<64;o<<=1) ss += __shfl_xor(ss, o, 64);
  __shared__ float sred[4];
  if ((tid & 63) == 0) sred[tid>>6] = ss;
  __syncthreads();
  float rstd = rsqrtf((sred[0]+sred[1]+sred[2]+sred[3]) * (1.f/2048.f) + 1e-5f);
  bf16x8 zv = *reinterpret_cast<const bf16x8*>(&zbuf[(size_t)row*2048 + c]);
  bf16x8 o;
  #pragma unroll
  for (int i=0;i<8;i++){
    float z = bf2f((u16)zv[i]);
    float sz = z / (1.f + __expf(-z));
    o[i] = (short)f2bf(v[i]*rstd*rms_w[c+i]*sz);
  }
  *reinterpret_cast<bf16x8*>(&un[(size_t)row*2048 + c]) = o;
}

extern "C" void kernel_launch(void* const* d_in, const int* in_sizes, int n_in,
                              void* d_out, int out_size, void* d_ws, size_t ws_size,
                              hipStream_t stream)
{
  const float* u       = (const float*)d_in[0];
  const float* w_in    = (const float*)d_in[1];
  const float* conv_w  = (const float*)d_in[2];
  const float* conv_b  = (const float*)d_in[3];
  const float* dt_bias = (const float*)d_in[4];
  const float* A_log   = (const float*)d_in[5];
  const float* D_w     = (const float*)d_in[6];
  const float* D_b     = (const float*)d_in[7];
  const float* rms_w   = (const float*)d_in[8];
  const float* w_out   = (const float*)d_in[9];
  float* out = (float*)d_out;
  (void)in_sizes; (void)n_in; (void)out_size; (void)ws_size;

  char* ws = (char*)d_ws;
  u16*   zbuf = (u16*)(ws);                         // 8192x2048 bf16
  u16*   xbc  = (u16*)(ws + 33554432);              // 8192x2304 bf16 (dead after conv -> dB -> un)
  u16*   dtbuf= (u16*)(ws + 71303168);              // 8192x64  bf16
  u16*   xc   = (u16*)(ws + 72351744);              // 8192x2304 bf16
  u16*   ypF  = (u16*)(ws + 110100480);             // 8192x2048 bf16
  u16*   ypB  = (u16*)(ws + 143654912);             // 8192x2048 bf16
  float* Dsc  = (float*)(ws + 177209344);           // 8192x32 f32
  u16*   w2b  = (u16*)(ws + 178257920);             // 1024x2048 bf16
  u16*   dwb  = (u16*)(ws + 182452224);             // 32x2048 bf16
  float* csum = (float*)(ws + 182583296);           // 2 x 4096 f32
  u16*   wtb  = (u16*)(ws + 182616064);             // 7x2304 bf16
  // aliases
  u16*   ub   = ypF;
  u16*   w1b  = ypF + (size_t)8192*1024;
  u16*   dB   = xbc;
  u16*   un   = xbc;

  cvt_f32_bf16<<<8192,256,0,stream>>>(u,     ub,  8192*1024/4);
  cvt_f32_bf16<<<4416,256,0,stream>>>(w_in,  w1b, 4416*1024/4);
  cvt_f32_bf16<<<2048,256,0,stream>>>(w_out, w2b, 1024*2048/4);
  cvt_f32_bf16<<<64,  256,0,stream>>>(D_w,   dwb, 32*2048/4);
  conv_prep<<<63,256,0,stream>>>(conv_w, wtb);

  // zxBCdt = u @ in_proj_w^T  (split into zbuf / xbc / dtbuf)
  // 256x128 tile, 3-buf safe pipeline, 72KB LDS -> 2 blocks/CU; 1120 blocks.
  gemm_p<1,2,256,128,2,2><<<dim3(35,32),256,0,stream>>>(ub,1024, w1b,1024, nullptr,0,
                                                        8192,4416,1024, zbuf, xbc, dtbuf);
  // depthwise conv + silu -> xc
  conv_silu<<<9216,256,0,stream>>>(xbc, wtb, conv_b, xc);
  // Dscal = x_og @ D_w^T  (f32)
  gemm_bt<1,0><<<dim3(1,64),256,0,stream>>>(xc,2304, dwb,2048, Dsc,32,
                                            8192,32,2048, nullptr,nullptr,nullptr);
  // chunked SSD scan, per direction
  for (int dir=0; dir<2; ++dir){
    u16* yP = dir ? ypB : ypF;
    ssd_chunk <<<4096,256,0,stream>>>(xc, dtbuf, dt_bias, A_log, yP, dB, csum + dir*4096, dir);
    ssd_state <<<256, 256,0,stream>>>(dB, csum + dir*4096, A_log);
    ssd_yinter<<<4096,256,0,stream>>>(xc, dtbuf, dt_bias, A_log, dB, yP, dir);
  }
  // combine + D path + RMS + gate -> un
  fuse_rms<<<8192,256,0,stream>>>(ypF, ypB, xc, zbuf, un, Dsc, D_b, rms_w);
  // out = un @ outproj_w^T  (f32)
  // 128x128 tile, 3-buf, 48KB LDS -> 3 blocks/CU; grid 512 = 2/CU, tail-free.
  gemm_p<0,0,128,128,2,2><<<dim3(8,64),256,0,stream>>>(un,2048, w2b,2048, out,1024,
                                                       8192,1024,2048, nullptr,nullptr,nullptr);
}

// Round 9
// 427.914 us; speedup vs baseline: 1.1182x; 1.0496x over previous
//
#include <hip/hip_runtime.h>

typedef unsigned short u16;
typedef __attribute__((ext_vector_type(8))) short bf16x8;
typedef __attribute__((ext_vector_type(4))) float f32x4;

__device__ __forceinline__ float bf2f(u16 u){
  union { unsigned int i; float f; } x; x.i = ((unsigned int)u) << 16; return x.f;
}
__device__ __forceinline__ u16 f2bf(float f){
  union { float f; unsigned int i; } x; x.f = f;
  unsigned int r = x.i + 0x7fffu + ((x.i >> 16) & 1u);
  return (u16)(r >> 16);
}

template<int N> __device__ __forceinline__ void waitcnt_vm(){
  if constexpr (N==0)       asm volatile("s_waitcnt vmcnt(0)" ::: "memory");
  else if constexpr (N==4)  asm volatile("s_waitcnt vmcnt(4)" ::: "memory");
  else if constexpr (N==6)  asm volatile("s_waitcnt vmcnt(6)" ::: "memory");
  else if constexpr (N==8)  asm volatile("s_waitcnt vmcnt(8)" ::: "memory");
  else if constexpr (N==12) asm volatile("s_waitcnt vmcnt(12)" ::: "memory");
}

// ---------------- f32 -> bf16 convert (vectorized) ----------------
__global__ __launch_bounds__(256) void cvt_f32_bf16(const float* __restrict__ in,
                                                    u16* __restrict__ out, int n4){
  int i = blockIdx.x*256 + threadIdx.x;
  if (i < n4){
    float4 v = reinterpret_cast<const float4*>(in)[i];
    ushort4 o = make_ushort4(f2bf(v.x), f2bf(v.y), f2bf(v.z), f2bf(v.w));
    reinterpret_cast<ushort4*>(out)[i] = o;
  }
}

// ---------------- conv weight transpose: w[2304][7] -> wtb[7][2304] bf16 -----
__global__ __launch_bounds__(256) void conv_prep(const float* __restrict__ w,
                                                 u16* __restrict__ wtb){
  int i = blockIdx.x*256 + threadIdx.x;
  if (i < 2304*7){
    int ch = i / 7, t = i % 7;
    wtb[t*2304 + ch] = f2bf(w[i]);
  }
}

// ====== counted-vmcnt pipelined bf16 MFMA GEMM, BK=32, 3 LDS bufs ===========
// SAFE ordering (r8-proven): waitcnt vmcnt(LPS) -> s_barrier -> stage(t+2)
// -> comp(t). Occupancy-first: 48KB LDS -> 3 blocks/CU (12 waves/CU) so
// cross-block TLP hides ds_read/vmcnt/barrier latency (m114). Grid sized for
// ~97% tail utilization. T5 setprio. MODE 0: f32 out. MODE 2: split (gemm1).
template<int GUARD, int MODE, int BM, int BN, int NM, int NN>
__global__ __launch_bounds__(256, 3) void gemm_p(
    const u16* __restrict__ A, int lda,
    const u16* __restrict__ Bt, int ldb,
    void* __restrict__ Cp, int ldc,
    int M, int N, int K,
    u16* __restrict__ zb, u16* __restrict__ xb, u16* __restrict__ db_)
{
  constexpr int T   = 64*NM*NN;
  constexpr int MF  = BM/NM/16;
  constexpr int NF  = BN/NN/16;
  constexpr int LPS = (BM+BN)*4/T;       // gload_lds per thread per stage
  __shared__ __align__(16) u16 As[3][BM*32];
  __shared__ __align__(16) u16 Bs[3][BN*32];
  const int tid  = threadIdx.x;
  const int wid  = tid >> 6;
  const int lane = tid & 63;
  // XCD-chunked bijective swizzle (grids are multiples of 8)
  const int nwg = gridDim.x * gridDim.y;
  const int bid = blockIdx.y * gridDim.x + blockIdx.x;
  const int q8  = nwg >> 3;
  const int swz = (bid & 7)*q8 + (bid >> 3);
  const int m0 = (swz / gridDim.x) * BM;
  const int n0 = (swz % gridDim.x) * BN;
  const int wm = wid / NN;
  const int wn = wid % NN;
  const int lq = lane >> 4, lr = lane & 15;
  // read-side XOR (must match stage()'s source-column XOR)
  const int ce = (lq ^ ((lr&3) ^ ((lr>>2)&3))) * 8;

  f32x4 acc[MF][NF];
  #pragma unroll
  for (int m=0;m<MF;m++)
    #pragma unroll
    for (int n=0;n<NF;n++) acc[m][n] = (f32x4){0.f,0.f,0.f,0.f};

  auto stage = [&](int t){
    const int buf = t % 3;
    const int k0  = t << 5;
    #pragma unroll
    for (int i=0;i<(BM*4)/T;i++){
      int slot = i*T + tid;
      int row = slot >> 2, cg = slot & 3;
      int sc = cg ^ ((row&3) ^ ((row>>2)&3));
      const u16* ga = A + (size_t)(m0 + row)*lda + k0 + sc*8;
      __builtin_amdgcn_global_load_lds(
        (const __attribute__((address_space(1))) void*)ga,
        (__attribute__((address_space(3))) void*)&As[buf][slot*8], 16, 0, 0);
    }
    #pragma unroll
    for (int i=0;i<(BN*4)/T;i++){
      int slot = i*T + tid;
      int row = slot >> 2, cg = slot & 3;
      int gn = n0 + row;
      if (GUARD) gn = (gn < N) ? gn : (N-1);
      int sc = cg ^ ((row&3) ^ ((row>>2)&3));
      const u16* gb = Bt + (size_t)gn*ldb + k0 + sc*8;
      __builtin_amdgcn_global_load_lds(
        (const __attribute__((address_space(1))) void*)gb,
        (__attribute__((address_space(3))) void*)&Bs[buf][slot*8], 16, 0, 0);
    }
  };

  auto comp = [&](int t){
    const int buf = t % 3;
    bf16x8 af[MF], bfr[NF];
    #pragma unroll
    for (int m=0;m<MF;m++){
      int row = wm*(MF*16) + m*16 + lr;
      af[m] = *reinterpret_cast<const bf16x8*>(&As[buf][row*32 + ce]);
    }
    #pragma unroll
    for (int n=0;n<NF;n++){
      int row = wn*(NF*16) + n*16 + lr;
      bfr[n] = *reinterpret_cast<const bf16x8*>(&Bs[buf][row*32 + ce]);
    }
    __builtin_amdgcn_s_setprio(1);
    #pragma unroll
    for (int m=0;m<MF;m++)
      #pragma unroll
      for (int n=0;n<NF;n++)
        acc[m][n] = __builtin_amdgcn_mfma_f32_16x16x32_bf16(af[m], bfr[n], acc[m][n], 0,0,0);
    __builtin_amdgcn_s_setprio(0);
  };

  const int nt = K >> 5;                 // >= 4 for all our shapes
  stage(0); stage(1);
  for (int t=0; t<nt; ++t){
    if (t+1 < nt) waitcnt_vm<LPS>();
    else          waitcnt_vm<0>();
    asm volatile("s_barrier" ::: "memory");
    if (t+2 < nt) stage(t+2);
    comp(t);
  }

  #pragma unroll
  for (int m=0;m<MF;m++){
    int row = m0 + wm*(MF*16) + m*16 + lq*4;
    #pragma unroll
    for (int n=0;n<NF;n++){
      int col = n0 + wn*(NF*16) + n*16 + lr;
      if (!GUARD || col < N){
        #pragma unroll
        for (int j=0;j<4;j++){
          float v = acc[m][n][j];
          size_t r = (size_t)(row+j);
          if (MODE == 0)      ((float*)Cp)[r*ldc + col] = v;
          else if (MODE == 1) ((u16*)Cp)[r*ldc + col] = f2bf(v);
          else {
            u16 bv = f2bf(v);
            if (col < 2048)      zb[r*2048 + col] = bv;
            else if (col < 4352) xb[r*2304 + (col-2048)] = bv;
            else                 db_[r*64 + (col-4352)] = bv;
          }
        }
      }
    }
  }
}

// ---------------- old 128-tile GEMM (kept for the skinny Dscal matmul) ------
template<int GUARD, int MODE>
__global__ __launch_bounds__(256) void gemm_bt(
    const u16* __restrict__ A, int lda,
    const u16* __restrict__ Bt, int ldb,
    void* __restrict__ Cp, int ldc,
    int M, int N, int K,
    u16* __restrict__ zb, u16* __restrict__ xb, u16* __restrict__ db_)
{
  __shared__ __align__(16) u16 As[128*64];
  __shared__ __align__(16) u16 Bs[128*64];
  const int tid  = threadIdx.x;
  const int wid  = tid >> 6;
  const int lane = tid & 63;
  const int nwg = gridDim.x * gridDim.y;
  const int bid = blockIdx.y * gridDim.x + blockIdx.x;
  const int q8  = nwg >> 3;
  const int swz = (nwg >= 8) ? ((bid & 7)*q8 + (bid >> 3)) : bid;
  const int m0 = (swz / gridDim.x) * 128;
  const int n0 = (swz % gridDim.x) * 128;
  const int wr = wid >> 1, wc = wid & 1;
  const int lq = lane >> 4, lr = lane & 15;

  f32x4 acc[4][4];
  #pragma unroll
  for (int m=0;m<4;m++)
    #pragma unroll
    for (int n=0;n<4;n++) acc[m][n] = (f32x4){0.f,0.f,0.f,0.f};

  const int srow = wid*32 + (lane>>3);
  const int scol = (lane&7)*8;

  for (int k0=0; k0<K; k0+=64){
    #pragma unroll
    for (int i=0;i<4;i++){
      const u16* ga = A + (size_t)(m0 + srow + i*8)*lda + k0 + scol;
      __builtin_amdgcn_global_load_lds(
        (const __attribute__((address_space(1))) void*)ga,
        (__attribute__((address_space(3))) void*)&As[(wid*32+i*8)*64], 16, 0, 0);
    }
    #pragma unroll
    for (int i=0;i<4;i++){
      int gn = n0 + srow + i*8;
      if (GUARD) gn = (gn < N) ? gn : (N-1);
      const u16* gb = Bt + (size_t)gn*ldb + k0 + scol;
      __builtin_amdgcn_global_load_lds(
        (const __attribute__((address_space(1))) void*)gb,
        (__attribute__((address_space(3))) void*)&Bs[(wid*32+i*8)*64], 16, 0, 0);
    }
    __syncthreads();
    #pragma unroll
    for (int kk=0;kk<2;kk++){
      bf16x8 af[4], bfr[4];
      #pragma unroll
      for (int m=0;m<4;m++)
        af[m] = *reinterpret_cast<const bf16x8*>(&As[(wr*64 + m*16 + lr)*64 + kk*32 + lq*8]);
      #pragma unroll
      for (int n=0;n<4;n++)
        bfr[n] = *reinterpret_cast<const bf16x8*>(&Bs[(wc*64 + n*16 + lr)*64 + kk*32 + lq*8]);
      #pragma unroll
      for (int m=0;m<4;m++)
        #pragma unroll
        for (int n=0;n<4;n++)
          acc[m][n] = __builtin_amdgcn_mfma_f32_16x16x32_bf16(af[m], bfr[n], acc[m][n], 0,0,0);
    }
    __syncthreads();
  }

  #pragma unroll
  for (int m=0;m<4;m++){
    int row = m0 + wr*64 + m*16 + lq*4;
    #pragma unroll
    for (int n=0;n<4;n++){
      int col = n0 + wc*64 + n*16 + lr;
      if (!GUARD || col < N){
        #pragma unroll
        for (int j=0;j<4;j++){
          float v = acc[m][n][j];
          size_t r = (size_t)(row+j);
          if (MODE == 0)      ((float*)Cp)[r*ldc + col] = v;
          else if (MODE == 1) ((u16*)Cp)[r*ldc + col] = f2bf(v);
          else {
            u16 bv = f2bf(v);
            if (col < 2048)      zb[r*2048 + col] = bv;
            else if (col < 4352) xb[r*2304 + (col-2048)] = bv;
            else                 db_[r*64 + (col-4352)] = bv;
          }
        }
      }
    }
  }
}

// ---------------- depthwise conv7 (SAME) + bias + SiLU -> bf16 ----------------
__global__ __launch_bounds__(256) void conv_silu(
    const u16* __restrict__ xbc, const u16* __restrict__ wtb,
    const float* __restrict__ bias, u16* __restrict__ xc)
{
  const int bid = blockIdx.x;
  const int sb  = (bid & 7)*1152 + (bid >> 3);
  const int idx = sb*256 + threadIdx.x;       // < 8192*288
  const int g   = idx % 288;
  const int row = idx / 288;
  const int l = row & 4095;
  const int c = g*8;
  float a[8];
  float4 b0 = *reinterpret_cast<const float4*>(&bias[c]);
  float4 b1 = *reinterpret_cast<const float4*>(&bias[c+4]);
  a[0]=b0.x; a[1]=b0.y; a[2]=b0.z; a[3]=b0.w;
  a[4]=b1.x; a[5]=b1.y; a[6]=b1.z; a[7]=b1.w;
  #pragma unroll
  for (int t=0;t<7;t++){
    int ls = l + t - 3;
    if (ls >= 0 && ls < 4096){
      bf16x8 v  = *reinterpret_cast<const bf16x8*>(&xbc[(size_t)(row + t - 3)*2304 + c]);
      bf16x8 wv = *reinterpret_cast<const bf16x8*>(&wtb[t*2304 + c]);
      #pragma unroll
      for (int j=0;j<8;j++) a[j] += bf2f((u16)v[j]) * bf2f((u16)wv[j]);
    }
  }
  bf16x8 o;
  #pragma unroll
  for (int j=0;j<8;j++){
    float s = a[j]/(1.f+__expf(-a[j]));
    o[j] = (short)f2bf(s);
  }
  *reinterpret_cast<bf16x8*>(&xc[(size_t)row*2304 + c]) = o;
}

// ================= chunked SSD scan (Q=64) =================
__global__ __launch_bounds__(256) void ssd_chunk(
    const u16* __restrict__ xc, const u16* __restrict__ dtb,
    const float* __restrict__ dt_bias, const float* __restrict__ A_log,
    u16* __restrict__ yP, u16* __restrict__ dB, float* __restrict__ csum, int dir)
{
  const int c  = blockIdx.x & 63;
  const int th = blockIdx.x >> 6;
  const int h  = th & 31;
  const int b  = th >> 5;
  const int tid = threadIdx.x;
  const int wid = tid >> 6;
  const int lane = tid & 63;
  const int lq = lane >> 4, lr = lane & 15;

  __shared__ __align__(16) u16 Cs[64*64];
  __shared__ __align__(16) u16 Bls[64*64];
  __shared__ __align__(16) u16 Xt[64*64];
  __shared__ __align__(16) u16 Gm[64*64];
  __shared__ __align__(16) u16 Bwt[64*64];
  __shared__ float cum[64], dtl[64];

  const float Ah = -__expf(A_log[h]);

  for (int e = tid; e < 512; e += 256){
    int i = e >> 3, g = e & 7;
    int l = dir ? (4095 - (c*64+i)) : (c*64+i);
    size_t rb = (size_t)(b*4096 + l)*2304;
    *reinterpret_cast<bf16x8*>(&Bls[i*64+g*8]) =
        *reinterpret_cast<const bf16x8*>(&xc[rb + 2048 + dir*128 + g*8]);
    *reinterpret_cast<bf16x8*>(&Cs[i*64+g*8]) =
        *reinterpret_cast<const bf16x8*>(&xc[rb + 2112 + dir*128 + g*8]);
  }
  for (int e = tid; e < 512; e += 256){
    int i = e & 63, g = e >> 6;
    int l = dir ? (4095 - (c*64+i)) : (c*64+i);
    bf16x8 xv = *reinterpret_cast<const bf16x8*>(&xc[(size_t)(b*4096+l)*2304 + (size_t)h*64 + g*8]);
    #pragma unroll
    for (int j=0;j<8;j++) Xt[(g*8+j)*64 + i] = (u16)xv[j];
  }
  if (tid < 64){
    int i = tid;
    int l = dir ? (4095 - (c*64+i)) : (c*64+i);
    float raw = bf2f(dtb[(size_t)(b*4096+l)*64 + dir*32 + h]) + dt_bias[h];
    float dte = (raw > 20.f) ? raw : log1pf(__expf(raw));
    dtl[i] = dte;
    float s = dte;
    #pragma unroll
    for (int off=1; off<64; off<<=1){
      float o = __shfl_up(s, off, 64);
      if (i >= off) s += o;
    }
    cum[i] = s;
    if (i == 63) csum[blockIdx.x] = s;
  }
  __syncthreads();

  f32x4 g4[4];
  #pragma unroll
  for (int n=0;n<4;n++) g4[n] = (f32x4){0.f,0.f,0.f,0.f};
  #pragma unroll
  for (int kk=0;kk<2;kk++){
    bf16x8 ca = *reinterpret_cast<const bf16x8*>(&Cs[(wid*16+lr)*64 + kk*32 + lq*8]);
    #pragma unroll
    for (int n=0;n<4;n++){
      bf16x8 bb = *reinterpret_cast<const bf16x8*>(&Bls[(n*16+lr)*64 + kk*32 + lq*8]);
      g4[n] = __builtin_amdgcn_mfma_f32_16x16x32_bf16(ca, bb, g4[n], 0,0,0);
    }
  }
  #pragma unroll
  for (int n=0;n<4;n++){
    #pragma unroll
    for (int r=0;r<4;r++){
      int gi = wid*16 + lq*4 + r;
      int gj = n*16 + lr;
      float wgt = (gj <= gi) ? __expf(Ah*(cum[gi]-cum[gj]))*dtl[gj] : 0.f;
      Gm[gi*64+gj] = f2bf(g4[n][r]*wgt);
    }
  }
  float ctot = cum[63];
  for (int e = tid; e < 512; e += 256){
    int j = e & 63, g = e >> 6;
    float wj = __expf(Ah*(ctot - cum[j])) * dtl[j];
    bf16x8 bv = *reinterpret_cast<const bf16x8*>(&Bls[j*64 + g*8]);
    #pragma unroll
    for (int nn=0;nn<8;nn++) Bwt[(g*8+nn)*64 + j] = f2bf(wj * bf2f((u16)bv[nn]));
  }
  __syncthreads();

  f32x4 yi[4], db4[4];
  #pragma unroll
  for (int n=0;n<4;n++){ yi[n] = (f32x4){0.f,0.f,0.f,0.f}; db4[n] = (f32x4){0.f,0.f,0.f,0.f}; }
  #pragma unroll
  for (int kk=0;kk<2;kk++){
    bf16x8 ga = *reinterpret_cast<const bf16x8*>(&Gm[(wid*16+lr)*64 + kk*32 + lq*8]);
    bf16x8 xa = *reinterpret_cast<const bf16x8*>(&Xt[(wid*16+lr)*64 + kk*32 + lq*8]);
    #pragma unroll
    for (int n=0;n<4;n++){
      bf16x8 xb = *reinterpret_cast<const bf16x8*>(&Xt[(n*16+lr)*64 + kk*32 + lq*8]);
      yi[n] = __builtin_amdgcn_mfma_f32_16x16x32_bf16(ga, xb, yi[n], 0,0,0);
      bf16x8 wb = *reinterpret_cast<const bf16x8*>(&Bwt[(n*16+lr)*64 + kk*32 + lq*8]);
      db4[n] = __builtin_amdgcn_mfma_f32_16x16x32_bf16(xa, wb, db4[n], 0,0,0);
    }
  }
  #pragma unroll
  for (int n=0;n<4;n++){
    #pragma unroll
    for (int r=0;r<4;r++){
      int i = wid*16 + lq*4 + r;
      yP[(size_t)(b*4096 + c*64 + i)*2048 + (size_t)h*64 + n*16 + lr] = f2bf(yi[n][r]);
    }
  }
  u16* dst = dB + (size_t)blockIdx.x*4096;
  #pragma unroll
  for (int n=0;n<4;n++){
    #pragma unroll
    for (int r=0;r<4;r++){
      int p = wid*16 + lq*4 + r;
      dst[p*64 + n*16 + lr] = f2bf(db4[n][r]);
    }
  }
}

// Pass B1: sequential h-chain over chunks, slot-shift in-place.
__global__ __launch_bounds__(256) void ssd_state(
    u16* __restrict__ dB, const float* __restrict__ csum,
    const float* __restrict__ A_log)
{
  const int q = blockIdx.x & 3;
  const int task = blockIdx.x >> 2;
  const int h = task & 31;
  const float Ah = -__expf(A_log[h]);
  const int p  = q*16 + (threadIdx.x >> 4);
  const int nb = (threadIdx.x & 15) * 4;
  float h0=0.f, h1=0.f, h2=0.f, h3=0.f;
  for (int c=0; c<63; ++c){
    float P = __expf(Ah * csum[task*64 + c]);
    u16* ptr = dB + ((size_t)(task*64 + c))*4096 + p*64 + nb;
    ushort4 dv = *reinterpret_cast<const ushort4*>(ptr);
    h0 = P*h0 + bf2f(dv.x);
    h1 = P*h1 + bf2f(dv.y);
    h2 = P*h2 + bf2f(dv.z);
    h3 = P*h3 + bf2f(dv.w);
    *reinterpret_cast<ushort4*>(ptr) = make_ushort4(f2bf(h0),f2bf(h1),f2bf(h2),f2bf(h3));
  }
}

// Pass B2: y += cd[i] * (C @ h_in^T). chunk 0 skipped.
__global__ __launch_bounds__(256) void ssd_yinter(
    const u16* __restrict__ xc, const u16* __restrict__ dtb,
    const float* __restrict__ dt_bias, const float* __restrict__ A_log,
    const u16* __restrict__ dB, u16* __restrict__ yP, int dir)
{
  const int c  = blockIdx.x & 63;
  if (c == 0) return;
  const int th = blockIdx.x >> 6;
  const int h  = th & 31;
  const int b  = th >> 5;
  const int tid = threadIdx.x;
  const int wid = tid >> 6;
  const int lane = tid & 63;
  const int lq = lane >> 4, lr = lane & 15;

  __shared__ __align__(16) u16 Cs[64*64];
  __shared__ __align__(16) u16 Hs[64*64];
  __shared__ float cum[64];

  const float Ah = -__expf(A_log[h]);

  for (int e = tid; e < 512; e += 256){
    int i = e >> 3, g = e & 7;
    int l = dir ? (4095 - (c*64+i)) : (c*64+i);
    *reinterpret_cast<bf16x8*>(&Cs[i*64+g*8]) =
        *reinterpret_cast<const bf16x8*>(&xc[(size_t)(b*4096+l)*2304 + 2112 + dir*128 + g*8]);
    *reinterpret_cast<bf16x8*>(&Hs[e*8]) =
        *reinterpret_cast<const bf16x8*>(&dB[(size_t)(blockIdx.x-1)*4096 + e*8]);
  }
  if (tid < 64){
    int i = tid;
    int l = dir ? (4095 - (c*64+i)) : (c*64+i);
    float raw = bf2f(dtb[(size_t)(b*4096+l)*64 + dir*32 + h]) + dt_bias[h];
    float dte = (raw > 20.f) ? raw : log1pf(__expf(raw));
    float s = dte;
    #pragma unroll
    for (int off=1; off<64; off<<=1){
      float o = __shfl_up(s, off, 64);
      if (i >= off) s += o;
    }
    cum[i] = s;
  }
  __syncthreads();

  f32x4 acc[4];
  #pragma unroll
  for (int n=0;n<4;n++) acc[n] = (f32x4){0.f,0.f,0.f,0.f};
  #pragma unroll
  for (int kk=0;kk<2;kk++){
    bf16x8 ca = *reinterpret_cast<const bf16x8*>(&Cs[(wid*16+lr)*64 + kk*32 + lq*8]);
    #pragma unroll
    for (int n=0;n<4;n++){
      bf16x8 hb = *reinterpret_cast<const bf16x8*>(&Hs[(n*16+lr)*64 + kk*32 + lq*8]);
      acc[n] = __builtin_amdgcn_mfma_f32_16x16x32_bf16(ca, hb, acc[n], 0,0,0);
    }
  }
  #pragma unroll
  for (int n=0;n<4;n++){
    #pragma unroll
    for (int r=0;r<4;r++){
      int i = wid*16 + lq*4 + r;
      float cd = __expf(Ah*cum[i]);
      size_t a = (size_t)(b*4096 + c*64 + i)*2048 + (size_t)h*64 + n*16 + lr;
      yP[a] = f2bf(bf2f(yP[a]) + cd*acc[n][r]);
    }
  }
}

// ---------------- fuse: y-combine(shift/flip) + D*x + RMSNorm + SiLU(z) ------
__global__ __launch_bounds__(256) void fuse_rms(
    const u16* __restrict__ ypF, const u16* __restrict__ ypB,
    const u16* __restrict__ xc, const u16* __restrict__ zbuf,
    u16* __restrict__ un,
    const float* __restrict__ Dscal, const float* __restrict__ D_b,
    const float* __restrict__ rms_w)
{
  const int row = blockIdx.x;
  const int l = row & 4095;
  const int tid = threadIdx.x;
  const int c = tid*8;
  const int hh = tid >> 3;
  float v[8]; float ss = 0.f;
  const bool hasF = (l >= 1);
  const bool hasB = (l <= 4094);
  bf16x8 yf, yb;
  if (hasF) yf = *reinterpret_cast<const bf16x8*>(&ypF[(size_t)(row-1)*2048 + c]);
  if (hasB) yb = *reinterpret_cast<const bf16x8*>(&ypB[(size_t)(row + 4094 - 2*l)*2048 + c]);
  bf16x8 xv = *reinterpret_cast<const bf16x8*>(&xc[(size_t)row*2304 + c]);
  const float dsc = Dscal[(size_t)row*32 + hh] + D_b[hh];
  #pragma unroll
  for (int i=0;i<8;i++){
    float y = hasF ? bf2f((u16)yf[i]) : 0.f;
    if (hasB) y += bf2f((u16)yb[i]);
    y += dsc * bf2f((u16)xv[i]);
    v[i] = y;
    ss += y*y;
  }
  #pragma unroll
  for (int o=1;o<64;o<<=1) ss += __shfl_xor(ss, o, 64);
  __shared__ float sred[4];
  if ((tid & 63) == 0) sred[tid>>6] = ss;
  __syncthreads();
  float rstd = rsqrtf((sred[0]+sred[1]+sred[2]+sred[3]) * (1.f/2048.f) + 1e-5f);
  bf16x8 zv = *reinterpret_cast<const bf16x8*>(&zbuf[(size_t)row*2048 + c]);
  bf16x8 o;
  #pragma unroll
  for (int i=0;i<8;i++){
    float z = bf2f((u16)zv[i]);
    float sz = z / (1.f + __expf(-z));
    o[i] = (short)f2bf(v[i]*rstd*rms_w[c+i]*sz);
  }
  *reinterpret_cast<bf16x8*>(&un[(size_t)row*2048 + c]) = o;
}

extern "C" void kernel_launch(void* const* d_in, const int* in_sizes, int n_in,
                              void* d_out, int out_size, void* d_ws, size_t ws_size,
                              hipStream_t stream)
{
  const float* u       = (const float*)d_in[0];
  const float* w_in    = (const float*)d_in[1];
  const float* conv_w  = (const float*)d_in[2];
  const float* conv_b  = (const float*)d_in[3];
  const float* dt_bias = (const float*)d_in[4];
  const float* A_log   = (const float*)d_in[5];
  const float* D_w     = (const float*)d_in[6];
  const float* D_b     = (const float*)d_in[7];
  const float* rms_w   = (const float*)d_in[8];
  const float* w_out   = (const float*)d_in[9];
  float* out = (float*)d_out;
  (void)in_sizes; (void)n_in; (void)out_size; (void)ws_size;

  char* ws = (char*)d_ws;
  u16*   zbuf = (u16*)(ws);                         // 8192x2048 bf16
  u16*   xbc  = (u16*)(ws + 33554432);              // 8192x2304 bf16 (dead after conv -> dB -> un)
  u16*   dtbuf= (u16*)(ws + 71303168);              // 8192x64  bf16
  u16*   xc   = (u16*)(ws + 72351744);              // 8192x2304 bf16
  u16*   ypF  = (u16*)(ws + 110100480);             // 8192x2048 bf16
  u16*   ypB  = (u16*)(ws + 143654912);             // 8192x2048 bf16
  float* Dsc  = (float*)(ws + 177209344);           // 8192x32 f32
  u16*   w2b  = (u16*)(ws + 178257920);             // 1024x2048 bf16
  u16*   dwb  = (u16*)(ws + 182452224);             // 32x2048 bf16
  float* csum = (float*)(ws + 182583296);           // 2 x 4096 f32
  u16*   wtb  = (u16*)(ws + 182616064);             // 7x2304 bf16
  // aliases
  u16*   ub   = ypF;
  u16*   w1b  = ypF + (size_t)8192*1024;
  u16*   dB   = xbc;
  u16*   un   = xbc;

  cvt_f32_bf16<<<8192,256,0,stream>>>(u,     ub,  8192*1024/4);
  cvt_f32_bf16<<<4416,256,0,stream>>>(w_in,  w1b, 4416*1024/4);
  cvt_f32_bf16<<<2048,256,0,stream>>>(w_out, w2b, 1024*2048/4);
  cvt_f32_bf16<<<64,  256,0,stream>>>(D_w,   dwb, 32*2048/4);
  conv_prep<<<63,256,0,stream>>>(conv_w, wtb);

  // zxBCdt = u @ in_proj_w^T  (split into zbuf / xbc / dtbuf)
  // 128x128 tile, 3-buf safe pipeline, 48KB LDS -> 3 blocks/CU (12 waves/CU);
  // grid 2240 blocks -> 2.92 rounds at 768 concurrent -> ~97% tail util.
  gemm_p<1,2,128,128,2,2><<<dim3(35,64),256,0,stream>>>(ub,1024, w1b,1024, nullptr,0,
                                                        8192,4416,1024, zbuf, xbc, dtbuf);
  // depthwise conv + silu -> xc
  conv_silu<<<9216,256,0,stream>>>(xbc, wtb, conv_b, xc);
  // Dscal = x_og @ D_w^T  (f32)
  gemm_bt<1,0><<<dim3(1,64),256,0,stream>>>(xc,2304, dwb,2048, Dsc,32,
                                            8192,32,2048, nullptr,nullptr,nullptr);
  // chunked SSD scan, per direction
  for (int dir=0; dir<2; ++dir){
    u16* yP = dir ? ypB : ypF;
    ssd_chunk <<<4096,256,0,stream>>>(xc, dtbuf, dt_bias, A_log, yP, dB, csum + dir*4096, dir);
    ssd_state <<<256, 256,0,stream>>>(dB, csum + dir*4096, A_log);
    ssd_yinter<<<4096,256,0,stream>>>(xc, dtbuf, dt_bias, A_log, dB, yP, dir);
  }
  // combine + D path + RMS + gate -> un
  fuse_rms<<<8192,256,0,stream>>>(ypF, ypB, xc, zbuf, un, Dsc, D_b, rms_w);
  // out = un @ outproj_w^T  (f32)
  // 128x128 tile, 3-buf, 48KB LDS -> 3 blocks/CU; grid 512 = 2/CU, tail-free.
  gemm_p<0,0,128,128,2,2><<<dim3(8,64),256,0,stream>>>(un,2048, w2b,2048, out,1024,
                                                       8192,1024,2048, nullptr,nullptr,nullptr);
}

// Round 10
// 425.174 us; speedup vs baseline: 1.1254x; 1.0064x over previous
//
#include <hip/hip_runtime.h>

typedef unsigned short u16;
typedef __attribute__((ext_vector_type(8))) short bf16x8;
typedef __attribute__((ext_vector_type(4))) float f32x4;

__device__ __forceinline__ float bf2f(u16 u){
  union { unsigned int i; float f; } x; x.i = ((unsigned int)u) << 16; return x.f;
}
__device__ __forceinline__ u16 f2bf(float f){
  union { float f; unsigned int i; } x; x.f = f;
  unsigned int r = x.i + 0x7fffu + ((x.i >> 16) & 1u);
  return (u16)(r >> 16);
}

template<int N> __device__ __forceinline__ void waitcnt_vm(){
  if constexpr (N==0)       asm volatile("s_waitcnt vmcnt(0)" ::: "memory");
  else if constexpr (N==4)  asm volatile("s_waitcnt vmcnt(4)" ::: "memory");
  else if constexpr (N==6)  asm volatile("s_waitcnt vmcnt(6)" ::: "memory");
  else if constexpr (N==8)  asm volatile("s_waitcnt vmcnt(8)" ::: "memory");
  else if constexpr (N==12) asm volatile("s_waitcnt vmcnt(12)" ::: "memory");
}

// ---------------- f32 -> bf16 convert (vectorized) ----------------
__global__ __launch_bounds__(256) void cvt_f32_bf16(const float* __restrict__ in,
                                                    u16* __restrict__ out, int n4){
  int i = blockIdx.x*256 + threadIdx.x;
  if (i < n4){
    float4 v = reinterpret_cast<const float4*>(in)[i];
    ushort4 o = make_ushort4(f2bf(v.x), f2bf(v.y), f2bf(v.z), f2bf(v.w));
    reinterpret_cast<ushort4*>(out)[i] = o;
  }
}

// ---------------- conv weight transpose: w[2304][7] -> wtb[7][2304] bf16 -----
__global__ __launch_bounds__(256) void conv_prep(const float* __restrict__ w,
                                                 u16* __restrict__ wtb){
  int i = blockIdx.x*256 + threadIdx.x;
  if (i < 2304*7){
    int ch = i / 7, t = i % 7;
    wtb[t*2304 + ch] = f2bf(w[i]);
  }
}

// ====== counted-vmcnt pipelined bf16 MFMA GEMM, BK=32, 3 LDS bufs ===========
// SAFE ordering (r8-proven): waitcnt vmcnt(LPS) -> s_barrier -> stage(t+2)
// -> comp(t). 48KB LDS -> 3 blocks/CU (TLP, m114). L2-locality mapping:
// within each XCD, m varies FASTEST so the current B-tile stays hot in the
// XCD's private 4MB L2 across mPerX m-blocks (r9: n-fastest cycled 9MB of
// B-tiles -> 4.4x over-fetch + ~900cy HBM-miss latency the pipeline can't
// hide). Requires gridDim.y % 8 == 0. MODE 0: f32 out. MODE 2: split (gemm1).
template<int GUARD, int MODE, int BM, int BN, int NM, int NN>
__global__ __launch_bounds__(256, 3) void gemm_p(
    const u16* __restrict__ A, int lda,
    const u16* __restrict__ Bt, int ldb,
    void* __restrict__ Cp, int ldc,
    int M, int N, int K,
    u16* __restrict__ zb, u16* __restrict__ xb, u16* __restrict__ db_)
{
  constexpr int T   = 64*NM*NN;
  constexpr int MF  = BM/NM/16;
  constexpr int NF  = BN/NN/16;
  constexpr int LPS = (BM+BN)*4/T;       // gload_lds per thread per stage
  __shared__ __align__(16) u16 As[3][BM*32];
  __shared__ __align__(16) u16 Bs[3][BN*32];
  const int tid  = threadIdx.x;
  const int wid  = tid >> 6;
  const int lane = tid & 63;
  // XCD-chunked bijective mapping, m-fastest within XCD (L2 B-tile reuse)
  const int bid   = blockIdx.y * gridDim.x + blockIdx.x;
  const int xcd   = bid & 7;
  const int local = bid >> 3;
  const int mPerX = gridDim.y >> 3;      // m-tiles owned by one XCD
  const int m0 = (xcd*mPerX + (local % mPerX)) * BM;
  const int n0 = (local / mPerX) * BN;
  const int wm = wid / NN;
  const int wn = wid % NN;
  const int lq = lane >> 4, lr = lane & 15;
  // read-side XOR (must match stage()'s source-column XOR)
  const int ce = (lq ^ ((lr&3) ^ ((lr>>2)&3))) * 8;

  f32x4 acc[MF][NF];
  #pragma unroll
  for (int m=0;m<MF;m++)
    #pragma unroll
    for (int n=0;n<NF;n++) acc[m][n] = (f32x4){0.f,0.f,0.f,0.f};

  auto stage = [&](int t){
    const int buf = t % 3;
    const int k0  = t << 5;
    #pragma unroll
    for (int i=0;i<(BM*4)/T;i++){
      int slot = i*T + tid;
      int row = slot >> 2, cg = slot & 3;
      int sc = cg ^ ((row&3) ^ ((row>>2)&3));
      const u16* ga = A + (size_t)(m0 + row)*lda + k0 + sc*8;
      __builtin_amdgcn_global_load_lds(
        (const __attribute__((address_space(1))) void*)ga,
        (__attribute__((address_space(3))) void*)&As[buf][slot*8], 16, 0, 0);
    }
    #pragma unroll
    for (int i=0;i<(BN*4)/T;i++){
      int slot = i*T + tid;
      int row = slot >> 2, cg = slot & 3;
      int gn = n0 + row;
      if (GUARD) gn = (gn < N) ? gn : (N-1);
      int sc = cg ^ ((row&3) ^ ((row>>2)&3));
      const u16* gb = Bt + (size_t)gn*ldb + k0 + sc*8;
      __builtin_amdgcn_global_load_lds(
        (const __attribute__((address_space(1))) void*)gb,
        (__attribute__((address_space(3))) void*)&Bs[buf][slot*8], 16, 0, 0);
    }
  };

  auto comp = [&](int t){
    const int buf = t % 3;
    bf16x8 af[MF], bfr[NF];
    #pragma unroll
    for (int m=0;m<MF;m++){
      int row = wm*(MF*16) + m*16 + lr;
      af[m] = *reinterpret_cast<const bf16x8*>(&As[buf][row*32 + ce]);
    }
    #pragma unroll
    for (int n=0;n<NF;n++){
      int row = wn*(NF*16) + n*16 + lr;
      bfr[n] = *reinterpret_cast<const bf16x8*>(&Bs[buf][row*32 + ce]);
    }
    __builtin_amdgcn_s_setprio(1);
    #pragma unroll
    for (int m=0;m<MF;m++)
      #pragma unroll
      for (int n=0;n<NF;n++)
        acc[m][n] = __builtin_amdgcn_mfma_f32_16x16x32_bf16(af[m], bfr[n], acc[m][n], 0,0,0);
    __builtin_amdgcn_s_setprio(0);
  };

  const int nt = K >> 5;                 // >= 4 for all our shapes
  stage(0); stage(1);
  for (int t=0; t<nt; ++t){
    if (t+1 < nt) waitcnt_vm<LPS>();
    else          waitcnt_vm<0>();
    asm volatile("s_barrier" ::: "memory");
    if (t+2 < nt) stage(t+2);
    comp(t);
  }

  #pragma unroll
  for (int m=0;m<MF;m++){
    int row = m0 + wm*(MF*16) + m*16 + lq*4;
    #pragma unroll
    for (int n=0;n<NF;n++){
      int col = n0 + wn*(NF*16) + n*16 + lr;
      if (!GUARD || col < N){
        #pragma unroll
        for (int j=0;j<4;j++){
          float v = acc[m][n][j];
          size_t r = (size_t)(row+j);
          if (MODE == 0)      ((float*)Cp)[r*ldc + col] = v;
          else if (MODE == 1) ((u16*)Cp)[r*ldc + col] = f2bf(v);
          else {
            u16 bv = f2bf(v);
            if (col < 2048)      zb[r*2048 + col] = bv;
            else if (col < 4352) xb[r*2304 + (col-2048)] = bv;
            else                 db_[r*64 + (col-4352)] = bv;
          }
        }
      }
    }
  }
}

// ---------------- old 128-tile GEMM (kept for the skinny Dscal matmul) ------
template<int GUARD, int MODE>
__global__ __launch_bounds__(256) void gemm_bt(
    const u16* __restrict__ A, int lda,
    const u16* __restrict__ Bt, int ldb,
    void* __restrict__ Cp, int ldc,
    int M, int N, int K,
    u16* __restrict__ zb, u16* __restrict__ xb, u16* __restrict__ db_)
{
  __shared__ __align__(16) u16 As[128*64];
  __shared__ __align__(16) u16 Bs[128*64];
  const int tid  = threadIdx.x;
  const int wid  = tid >> 6;
  const int lane = tid & 63;
  const int nwg = gridDim.x * gridDim.y;
  const int bid = blockIdx.y * gridDim.x + blockIdx.x;
  const int q8  = nwg >> 3;
  const int swz = (nwg >= 8) ? ((bid & 7)*q8 + (bid >> 3)) : bid;
  const int m0 = (swz / gridDim.x) * 128;
  const int n0 = (swz % gridDim.x) * 128;
  const int wr = wid >> 1, wc = wid & 1;
  const int lq = lane >> 4, lr = lane & 15;

  f32x4 acc[4][4];
  #pragma unroll
  for (int m=0;m<4;m++)
    #pragma unroll
    for (int n=0;n<4;n++) acc[m][n] = (f32x4){0.f,0.f,0.f,0.f};

  const int srow = wid*32 + (lane>>3);
  const int scol = (lane&7)*8;

  for (int k0=0; k0<K; k0+=64){
    #pragma unroll
    for (int i=0;i<4;i++){
      const u16* ga = A + (size_t)(m0 + srow + i*8)*lda + k0 + scol;
      __builtin_amdgcn_global_load_lds(
        (const __attribute__((address_space(1))) void*)ga,
        (__attribute__((address_space(3))) void*)&As[(wid*32+i*8)*64], 16, 0, 0);
    }
    #pragma unroll
    for (int i=0;i<4;i++){
      int gn = n0 + srow + i*8;
      if (GUARD) gn = (gn < N) ? gn : (N-1);
      const u16* gb = Bt + (size_t)gn*ldb + k0 + scol;
      __builtin_amdgcn_global_load_lds(
        (const __attribute__((address_space(1))) void*)gb,
        (__attribute__((address_space(3))) void*)&Bs[(wid*32+i*8)*64], 16, 0, 0);
    }
    __syncthreads();
    #pragma unroll
    for (int kk=0;kk<2;kk++){
      bf16x8 af[4], bfr[4];
      #pragma unroll
      for (int m=0;m<4;m++)
        af[m] = *reinterpret_cast<const bf16x8*>(&As[(wr*64 + m*16 + lr)*64 + kk*32 + lq*8]);
      #pragma unroll
      for (int n=0;n<4;n++)
        bfr[n] = *reinterpret_cast<const bf16x8*>(&Bs[(wc*64 + n*16 + lr)*64 + kk*32 + lq*8]);
      #pragma unroll
      for (int m=0;m<4;m++)
        #pragma unroll
        for (int n=0;n<4;n++)
          acc[m][n] = __builtin_amdgcn_mfma_f32_16x16x32_bf16(af[m], bfr[n], acc[m][n], 0,0,0);
    }
    __syncthreads();
  }

  #pragma unroll
  for (int m=0;m<4;m++){
    int row = m0 + wr*64 + m*16 + lq*4;
    #pragma unroll
    for (int n=0;n<4;n++){
      int col = n0 + wc*64 + n*16 + lr;
      if (!GUARD || col < N){
        #pragma unroll
        for (int j=0;j<4;j++){
          float v = acc[m][n][j];
          size_t r = (size_t)(row+j);
          if (MODE == 0)      ((float*)Cp)[r*ldc + col] = v;
          else if (MODE == 1) ((u16*)Cp)[r*ldc + col] = f2bf(v);
          else {
            u16 bv = f2bf(v);
            if (col < 2048)      zb[r*2048 + col] = bv;
            else if (col < 4352) xb[r*2304 + (col-2048)] = bv;
            else                 db_[r*64 + (col-4352)] = bv;
          }
        }
      }
    }
  }
}

// ---------------- depthwise conv7 (SAME) + bias + SiLU -> bf16 ----------------
__global__ __launch_bounds__(256) void conv_silu(
    const u16* __restrict__ xbc, const u16* __restrict__ wtb,
    const float* __restrict__ bias, u16* __restrict__ xc)
{
  const int bid = blockIdx.x;
  const int sb  = (bid & 7)*1152 + (bid >> 3);
  const int idx = sb*256 + threadIdx.x;       // < 8192*288
  const int g   = idx % 288;
  const int row = idx / 288;
  const int l = row & 4095;
  const int c = g*8;
  float a[8];
  float4 b0 = *reinterpret_cast<const float4*>(&bias[c]);
  float4 b1 = *reinterpret_cast<const float4*>(&bias[c+4]);
  a[0]=b0.x; a[1]=b0.y; a[2]=b0.z; a[3]=b0.w;
  a[4]=b1.x; a[5]=b1.y; a[6]=b1.z; a[7]=b1.w;
  #pragma unroll
  for (int t=0;t<7;t++){
    int ls = l + t - 3;
    if (ls >= 0 && ls < 4096){
      bf16x8 v  = *reinterpret_cast<const bf16x8*>(&xbc[(size_t)(row + t - 3)*2304 + c]);
      bf16x8 wv = *reinterpret_cast<const bf16x8*>(&wtb[t*2304 + c]);
      #pragma unroll
      for (int j=0;j<8;j++) a[j] += bf2f((u16)v[j]) * bf2f((u16)wv[j]);
    }
  }
  bf16x8 o;
  #pragma unroll
  for (int j=0;j<8;j++){
    float s = a[j]/(1.f+__expf(-a[j]));
    o[j] = (short)f2bf(s);
  }
  *reinterpret_cast<bf16x8*>(&xc[(size_t)row*2304 + c]) = o;
}

// ================= chunked SSD scan (Q=64) =================
__global__ __launch_bounds__(256) void ssd_chunk(
    const u16* __restrict__ xc, const u16* __restrict__ dtb,
    const float* __restrict__ dt_bias, const float* __restrict__ A_log,
    u16* __restrict__ yP, u16* __restrict__ dB, float* __restrict__ csum, int dir)
{
  const int c  = blockIdx.x & 63;
  const int th = blockIdx.x >> 6;
  const int h  = th & 31;
  const int b  = th >> 5;
  const int tid = threadIdx.x;
  const int wid = tid >> 6;
  const int lane = tid & 63;
  const int lq = lane >> 4, lr = lane & 15;

  __shared__ __align__(16) u16 Cs[64*64];
  __shared__ __align__(16) u16 Bls[64*64];
  __shared__ __align__(16) u16 Xt[64*64];
  __shared__ __align__(16) u16 Gm[64*64];
  __shared__ __align__(16) u16 Bwt[64*64];
  __shared__ float cum[64], dtl[64];

  const float Ah = -__expf(A_log[h]);

  for (int e = tid; e < 512; e += 256){
    int i = e >> 3, g = e & 7;
    int l = dir ? (4095 - (c*64+i)) : (c*64+i);
    size_t rb = (size_t)(b*4096 + l)*2304;
    *reinterpret_cast<bf16x8*>(&Bls[i*64+g*8]) =
        *reinterpret_cast<const bf16x8*>(&xc[rb + 2048 + dir*128 + g*8]);
    *reinterpret_cast<bf16x8*>(&Cs[i*64+g*8]) =
        *reinterpret_cast<const bf16x8*>(&xc[rb + 2112 + dir*128 + g*8]);
  }
  for (int e = tid; e < 512; e += 256){
    int i = e & 63, g = e >> 6;
    int l = dir ? (4095 - (c*64+i)) : (c*64+i);
    bf16x8 xv = *reinterpret_cast<const bf16x8*>(&xc[(size_t)(b*4096+l)*2304 + (size_t)h*64 + g*8]);
    #pragma unroll
    for (int j=0;j<8;j++) Xt[(g*8+j)*64 + i] = (u16)xv[j];
  }
  if (tid < 64){
    int i = tid;
    int l = dir ? (4095 - (c*64+i)) : (c*64+i);
    float raw = bf2f(dtb[(size_t)(b*4096+l)*64 + dir*32 + h]) + dt_bias[h];
    float dte = (raw > 20.f) ? raw : log1pf(__expf(raw));
    dtl[i] = dte;
    float s = dte;
    #pragma unroll
    for (int off=1; off<64; off<<=1){
      float o = __shfl_up(s, off, 64);
      if (i >= off) s += o;
    }
    cum[i] = s;
    if (i == 63) csum[blockIdx.x] = s;
  }
  __syncthreads();

  f32x4 g4[4];
  #pragma unroll
  for (int n=0;n<4;n++) g4[n] = (f32x4){0.f,0.f,0.f,0.f};
  #pragma unroll
  for (int kk=0;kk<2;kk++){
    bf16x8 ca = *reinterpret_cast<const bf16x8*>(&Cs[(wid*16+lr)*64 + kk*32 + lq*8]);
    #pragma unroll
    for (int n=0;n<4;n++){
      bf16x8 bb = *reinterpret_cast<const bf16x8*>(&Bls[(n*16+lr)*64 + kk*32 + lq*8]);
      g4[n] = __builtin_amdgcn_mfma_f32_16x16x32_bf16(ca, bb, g4[n], 0,0,0);
    }
  }
  #pragma unroll
  for (int n=0;n<4;n++){
    #pragma unroll
    for (int r=0;r<4;r++){
      int gi = wid*16 + lq*4 + r;
      int gj = n*16 + lr;
      float wgt = (gj <= gi) ? __expf(Ah*(cum[gi]-cum[gj]))*dtl[gj] : 0.f;
      Gm[gi*64+gj] = f2bf(g4[n][r]*wgt);
    }
  }
  float ctot = cum[63];
  for (int e = tid; e < 512; e += 256){
    int j = e & 63, g = e >> 6;
    float wj = __expf(Ah*(ctot - cum[j])) * dtl[j];
    bf16x8 bv = *reinterpret_cast<const bf16x8*>(&Bls[j*64 + g*8]);
    #pragma unroll
    for (int nn=0;nn<8;nn++) Bwt[(g*8+nn)*64 + j] = f2bf(wj * bf2f((u16)bv[nn]));
  }
  __syncthreads();

  f32x4 yi[4], db4[4];
  #pragma unroll
  for (int n=0;n<4;n++){ yi[n] = (f32x4){0.f,0.f,0.f,0.f}; db4[n] = (f32x4){0.f,0.f,0.f,0.f}; }
  #pragma unroll
  for (int kk=0;kk<2;kk++){
    bf16x8 ga = *reinterpret_cast<const bf16x8*>(&Gm[(wid*16+lr)*64 + kk*32 + lq*8]);
    bf16x8 xa = *reinterpret_cast<const bf16x8*>(&Xt[(wid*16+lr)*64 + kk*32 + lq*8]);
    #pragma unroll
    for (int n=0;n<4;n++){
      bf16x8 xb = *reinterpret_cast<const bf16x8*>(&Xt[(n*16+lr)*64 + kk*32 + lq*8]);
      yi[n] = __builtin_amdgcn_mfma_f32_16x16x32_bf16(ga, xb, yi[n], 0,0,0);
      bf16x8 wb = *reinterpret_cast<const bf16x8*>(&Bwt[(n*16+lr)*64 + kk*32 + lq*8]);
      db4[n] = __builtin_amdgcn_mfma_f32_16x16x32_bf16(xa, wb, db4[n], 0,0,0);
    }
  }
  #pragma unroll
  for (int n=0;n<4;n++){
    #pragma unroll
    for (int r=0;r<4;r++){
      int i = wid*16 + lq*4 + r;
      yP[(size_t)(b*4096 + c*64 + i)*2048 + (size_t)h*64 + n*16 + lr] = f2bf(yi[n][r]);
    }
  }
  u16* dst = dB + (size_t)blockIdx.x*4096;
  #pragma unroll
  for (int n=0;n<4;n++){
    #pragma unroll
    for (int r=0;r<4;r++){
      int p = wid*16 + lq*4 + r;
      dst[p*64 + n*16 + lr] = f2bf(db4[n][r]);
    }
  }
}

// Pass B1: sequential h-chain over chunks, slot-shift in-place.
__global__ __launch_bounds__(256) void ssd_state(
    u16* __restrict__ dB, const float* __restrict__ csum,
    const float* __restrict__ A_log)
{
  const int q = blockIdx.x & 3;
  const int task = blockIdx.x >> 2;
  const int h = task & 31;
  const float Ah = -__expf(A_log[h]);
  const int p  = q*16 + (threadIdx.x >> 4);
  const int nb = (threadIdx.x & 15) * 4;
  float h0=0.f, h1=0.f, h2=0.f, h3=0.f;
  for (int c=0; c<63; ++c){
    float P = __expf(Ah * csum[task*64 + c]);
    u16* ptr = dB + ((size_t)(task*64 + c))*4096 + p*64 + nb;
    ushort4 dv = *reinterpret_cast<const ushort4*>(ptr);
    h0 = P*h0 + bf2f(dv.x);
    h1 = P*h1 + bf2f(dv.y);
    h2 = P*h2 + bf2f(dv.z);
    h3 = P*h3 + bf2f(dv.w);
    *reinterpret_cast<ushort4*>(ptr) = make_ushort4(f2bf(h0),f2bf(h1),f2bf(h2),f2bf(h3));
  }
}

// Pass B2: y += cd[i] * (C @ h_in^T). chunk 0 skipped.
__global__ __launch_bounds__(256) void ssd_yinter(
    const u16* __restrict__ xc, const u16* __restrict__ dtb,
    const float* __restrict__ dt_bias, const float* __restrict__ A_log,
    const u16* __restrict__ dB, u16* __restrict__ yP, int dir)
{
  const int c  = blockIdx.x & 63;
  if (c == 0) return;
  const int th = blockIdx.x >> 6;
  const int h  = th & 31;
  const int b  = th >> 5;
  const int tid = threadIdx.x;
  const int wid = tid >> 6;
  const int lane = tid & 63;
  const int lq = lane >> 4, lr = lane & 15;

  __shared__ __align__(16) u16 Cs[64*64];
  __shared__ __align__(16) u16 Hs[64*64];
  __shared__ float cum[64];

  const float Ah = -__expf(A_log[h]);

  for (int e = tid; e < 512; e += 256){
    int i = e >> 3, g = e & 7;
    int l = dir ? (4095 - (c*64+i)) : (c*64+i);
    *reinterpret_cast<bf16x8*>(&Cs[i*64+g*8]) =
        *reinterpret_cast<const bf16x8*>(&xc[(size_t)(b*4096+l)*2304 + 2112 + dir*128 + g*8]);
    *reinterpret_cast<bf16x8*>(&Hs[e*8]) =
        *reinterpret_cast<const bf16x8*>(&dB[(size_t)(blockIdx.x-1)*4096 + e*8]);
  }
  if (tid < 64){
    int i = tid;
    int l = dir ? (4095 - (c*64+i)) : (c*64+i);
    float raw = bf2f(dtb[(size_t)(b*4096+l)*64 + dir*32 + h]) + dt_bias[h];
    float dte = (raw > 20.f) ? raw : log1pf(__expf(raw));
    float s = dte;
    #pragma unroll
    for (int off=1; off<64; off<<=1){
      float o = __shfl_up(s, off, 64);
      if (i >= off) s += o;
    }
    cum[i] = s;
  }
  __syncthreads();

  f32x4 acc[4];
  #pragma unroll
  for (int n=0;n<4;n++) acc[n] = (f32x4){0.f,0.f,0.f,0.f};
  #pragma unroll
  for (int kk=0;kk<2;kk++){
    bf16x8 ca = *reinterpret_cast<const bf16x8*>(&Cs[(wid*16+lr)*64 + kk*32 + lq*8]);
    #pragma unroll
    for (int n=0;n<4;n++){
      bf16x8 hb = *reinterpret_cast<const bf16x8*>(&Hs[(n*16+lr)*64 + kk*32 + lq*8]);
      acc[n] = __builtin_amdgcn_mfma_f32_16x16x32_bf16(ca, hb, acc[n], 0,0,0);
    }
  }
  #pragma unroll
  for (int n=0;n<4;n++){
    #pragma unroll
    for (int r=0;r<4;r++){
      int i = wid*16 + lq*4 + r;
      float cd = __expf(Ah*cum[i]);
      size_t a = (size_t)(b*4096 + c*64 + i)*2048 + (size_t)h*64 + n*16 + lr;
      yP[a] = f2bf(bf2f(yP[a]) + cd*acc[n][r]);
    }
  }
}

// ---------------- fuse: y-combine(shift/flip) + D*x + RMSNorm + SiLU(z) ------
__global__ __launch_bounds__(256) void fuse_rms(
    const u16* __restrict__ ypF, const u16* __restrict__ ypB,
    const u16* __restrict__ xc, const u16* __restrict__ zbuf,
    u16* __restrict__ un,
    const float* __restrict__ Dscal, const float* __restrict__ D_b,
    const float* __restrict__ rms_w)
{
  const int row = blockIdx.x;
  const int l = row & 4095;
  const int tid = threadIdx.x;
  const int c = tid*8;
  const int hh = tid >> 3;
  float v[8]; float ss = 0.f;
  const bool hasF = (l >= 1);
  const bool hasB = (l <= 4094);
  bf16x8 yf, yb;
  if (hasF) yf = *reinterpret_cast<const bf16x8*>(&ypF[(size_t)(row-1)*2048 + c]);
  if (hasB) yb = *reinterpret_cast<const bf16x8*>(&ypB[(size_t)(row + 4094 - 2*l)*2048 + c]);
  bf16x8 xv = *reinterpret_cast<const bf16x8*>(&xc[(size_t)row*2304 + c]);
  const float dsc = Dscal[(size_t)row*32 + hh] + D_b[hh];
  #pragma unroll
  for (int i=0;i<8;i++){
    float y = hasF ? bf2f((u16)yf[i]) : 0.f;
    if (hasB) y += bf2f((u16)yb[i]);
    y += dsc * bf2f((u16)xv[i]);
    v[i] = y;
    ss += y*y;
  }
  #pragma unroll
  for (int o=1;o<64;o<<=1) ss += __shfl_xor(ss, o, 64);
  __shared__ float sred[4];
  if ((tid & 63) == 0) sred[tid>>6] = ss;
  __syncthreads();
  float rstd = rsqrtf((sred[0]+sred[1]+sred[2]+sred[3]) * (1.f/2048.f) + 1e-5f);
  bf16x8 zv = *reinterpret_cast<const bf16x8*>(&zbuf[(size_t)row*2048 + c]);
  bf16x8 o;
  #pragma unroll
  for (int i=0;i<8;i++){
    float z = bf2f((u16)zv[i]);
    float sz = z / (1.f + __expf(-z));
    o[i] = (short)f2bf(v[i]*rstd*rms_w[c+i]*sz);
  }
  *reinterpret_cast<bf16x8*>(&un[(size_t)row*2048 + c]) = o;
}

extern "C" void kernel_launch(void* const* d_in, const int* in_sizes, int n_in,
                              void* d_out, int out_size, void* d_ws, size_t ws_size,
                              hipStream_t stream)
{
  const float* u       = (const float*)d_in[0];
  const float* w_in    = (const float*)d_in[1];
  const float* conv_w  = (const float*)d_in[2];
  const float* conv_b  = (const float*)d_in[3];
  const float* dt_bias = (const float*)d_in[4];
  const float* A_log   = (const float*)d_in[5];
  const float* D_w     = (const float*)d_in[6];
  const float* D_b     = (const float*)d_in[7];
  const float* rms_w   = (const float*)d_in[8];
  const float* w_out   = (const float*)d_in[9];
  float* out = (float*)d_out;
  (void)in_sizes; (void)n_in; (void)out_size; (void)ws_size;

  char* ws = (char*)d_ws;
  u16*   zbuf = (u16*)(ws);                         // 8192x2048 bf16
  u16*   xbc  = (u16*)(ws + 33554432);              // 8192x2304 bf16 (dead after conv -> dB -> un)
  u16*   dtbuf= (u16*)(ws + 71303168);              // 8192x64  bf16
  u16*   xc   = (u16*)(ws + 72351744);              // 8192x2304 bf16
  u16*   ypF  = (u16*)(ws + 110100480);             // 8192x2048 bf16
  u16*   ypB  = (u16*)(ws + 143654912);             // 8192x2048 bf16
  float* Dsc  = (float*)(ws + 177209344);           // 8192x32 f32
  u16*   w2b  = (u16*)(ws + 178257920);             // 1024x2048 bf16
  u16*   dwb  = (u16*)(ws + 182452224);             // 32x2048 bf16
  float* csum = (float*)(ws + 182583296);           // 2 x 4096 f32
  u16*   wtb  = (u16*)(ws + 182616064);             // 7x2304 bf16
  // aliases
  u16*   ub   = ypF;
  u16*   w1b  = ypF + (size_t)8192*1024;
  u16*   dB   = xbc;
  u16*   un   = xbc;

  cvt_f32_bf16<<<8192,256,0,stream>>>(u,     ub,  8192*1024/4);
  cvt_f32_bf16<<<4416,256,0,stream>>>(w_in,  w1b, 4416*1024/4);
  cvt_f32_bf16<<<2048,256,0,stream>>>(w_out, w2b, 1024*2048/4);
  cvt_f32_bf16<<<64,  256,0,stream>>>(D_w,   dwb, 32*2048/4);
  conv_prep<<<63,256,0,stream>>>(conv_w, wtb);

  // zxBCdt = u @ in_proj_w^T  (split into zbuf / xbc / dtbuf)
  // 128x128 tile, 3-buf safe pipeline, 48KB LDS -> 3 blocks/CU;
  // m-fastest XCD mapping: B-tile stays in per-XCD L2 across 8 m-blocks.
  gemm_p<1,2,128,128,2,2><<<dim3(35,64),256,0,stream>>>(ub,1024, w1b,1024, nullptr,0,
                                                        8192,4416,1024, zbuf, xbc, dtbuf);
  // depthwise conv + silu -> xc
  conv_silu<<<9216,256,0,stream>>>(xbc, wtb, conv_b, xc);
  // Dscal = x_og @ D_w^T  (f32)
  gemm_bt<1,0><<<dim3(1,64),256,0,stream>>>(xc,2304, dwb,2048, Dsc,32,
                                            8192,32,2048, nullptr,nullptr,nullptr);
  // chunked SSD scan, per direction
  for (int dir=0; dir<2; ++dir){
    u16* yP = dir ? ypB : ypF;
    ssd_chunk <<<4096,256,0,stream>>>(xc, dtbuf, dt_bias, A_log, yP, dB, csum + dir*4096, dir);
    ssd_state <<<256, 256,0,stream>>>(dB, csum + dir*4096, A_log);
    ssd_yinter<<<4096,256,0,stream>>>(xc, dtbuf, dt_bias, A_log, dB, yP, dir);
  }
  // combine + D path + RMS + gate -> un
  fuse_rms<<<8192,256,0,stream>>>(ypF, ypB, xc, zbuf, un, Dsc, D_b, rms_w);
  // out = un @ outproj_w^T  (f32)
  gemm_p<0,0,128,128,2,2><<<dim3(8,64),256,0,stream>>>(un,2048, w2b,2048, out,1024,
                                                       8192,1024,2048, nullptr,nullptr,nullptr);
}

// Round 11
// 425.163 us; speedup vs baseline: 1.1254x; 1.0000x over previous
//
#include <hip/hip_runtime.h>

typedef unsigned short u16;
typedef __attribute__((ext_vector_type(8))) short bf16x8;
typedef __attribute__((ext_vector_type(4))) float f32x4;

__device__ __forceinline__ float bf2f(u16 u){
  union { unsigned int i; float f; } x; x.i = ((unsigned int)u) << 16; return x.f;
}
__device__ __forceinline__ u16 f2bf(float f){
  union { float f; unsigned int i; } x; x.f = f;
  unsigned int r = x.i + 0x7fffu + ((x.i >> 16) & 1u);
  return (u16)(r >> 16);
}

template<int N> __device__ __forceinline__ void waitcnt_vm(){
  if constexpr (N==0)       asm volatile("s_waitcnt vmcnt(0)" ::: "memory");
  else if constexpr (N==3)  asm volatile("s_waitcnt vmcnt(3)" ::: "memory");
  else if constexpr (N==4)  asm volatile("s_waitcnt vmcnt(4)" ::: "memory");
  else if constexpr (N==6)  asm volatile("s_waitcnt vmcnt(6)" ::: "memory");
  else if constexpr (N==8)  asm volatile("s_waitcnt vmcnt(8)" ::: "memory");
  else if constexpr (N==12) asm volatile("s_waitcnt vmcnt(12)" ::: "memory");
}

// ---------------- f32 -> bf16 convert (vectorized) ----------------
__global__ __launch_bounds__(256) void cvt_f32_bf16(const float* __restrict__ in,
                                                    u16* __restrict__ out, int n4){
  int i = blockIdx.x*256 + threadIdx.x;
  if (i < n4){
    float4 v = reinterpret_cast<const float4*>(in)[i];
    ushort4 o = make_ushort4(f2bf(v.x), f2bf(v.y), f2bf(v.z), f2bf(v.w));
    reinterpret_cast<ushort4*>(out)[i] = o;
  }
}

// ---------------- conv weight transpose: w[2304][7] -> wtb[7][2304] bf16 -----
__global__ __launch_bounds__(256) void conv_prep(const float* __restrict__ w,
                                                 u16* __restrict__ wtb){
  int i = blockIdx.x*256 + threadIdx.x;
  if (i < 2304*7){
    int ch = i / 7, t = i % 7;
    wtb[t*2304 + ch] = f2bf(w[i]);
  }
}

// ====== counted-vmcnt pipelined bf16 MFMA GEMM, BK=32, 3 LDS bufs ===========
// SAFE ordering (r8-proven): waitcnt vmcnt(LPS) -> s_barrier -> stage(t+2)
// -> comp(t). Occupancy-first (m114 TLP): LDS small enough for 3-4 blocks/CU.
// m-fastest XCD mapping keeps B-tile hot in per-XCD L2 (r10: FETCH 116->60MB).
// Requires gridDim.y % 8 == 0. MODE 0: f32 out. MODE 2: split (gemm1).
template<int GUARD, int MODE, int BM, int BN, int NM, int NN>
__global__ __launch_bounds__(256, 3) void gemm_p(
    const u16* __restrict__ A, int lda,
    const u16* __restrict__ Bt, int ldb,
    void* __restrict__ Cp, int ldc,
    int M, int N, int K,
    u16* __restrict__ zb, u16* __restrict__ xb, u16* __restrict__ db_)
{
  constexpr int T   = 64*NM*NN;
  constexpr int MF  = BM/NM/16;
  constexpr int NF  = BN/NN/16;
  constexpr int LPS = (BM+BN)*4/T;       // gload_lds per thread per stage
  __shared__ __align__(16) u16 As[3][BM*32];
  __shared__ __align__(16) u16 Bs[3][BN*32];
  const int tid  = threadIdx.x;
  const int wid  = tid >> 6;
  const int lane = tid & 63;
  // XCD-chunked bijective mapping, m-fastest within XCD (L2 B-tile reuse)
  const int bid   = blockIdx.y * gridDim.x + blockIdx.x;
  const int xcd   = bid & 7;
  const int local = bid >> 3;
  const int mPerX = gridDim.y >> 3;      // m-tiles owned by one XCD
  const int m0 = (xcd*mPerX + (local % mPerX)) * BM;
  const int n0 = (local / mPerX) * BN;
  const int wm = wid / NN;
  const int wn = wid % NN;
  const int lq = lane >> 4, lr = lane & 15;
  // read-side XOR (must match stage()'s source-column XOR)
  const int ce = (lq ^ ((lr&3) ^ ((lr>>2)&3))) * 8;

  f32x4 acc[MF][NF];
  #pragma unroll
  for (int m=0;m<MF;m++)
    #pragma unroll
    for (int n=0;n<NF;n++) acc[m][n] = (f32x4){0.f,0.f,0.f,0.f};

  auto stage = [&](int t){
    const int buf = t % 3;
    const int k0  = t << 5;
    #pragma unroll
    for (int i=0;i<(BM*4)/T;i++){
      int slot = i*T + tid;
      int row = slot >> 2, cg = slot & 3;
      int sc = cg ^ ((row&3) ^ ((row>>2)&3));
      const u16* ga = A + (size_t)(m0 + row)*lda + k0 + sc*8;
      __builtin_amdgcn_global_load_lds(
        (const __attribute__((address_space(1))) void*)ga,
        (__attribute__((address_space(3))) void*)&As[buf][slot*8], 16, 0, 0);
    }
    #pragma unroll
    for (int i=0;i<(BN*4)/T;i++){
      int slot = i*T + tid;
      int row = slot >> 2, cg = slot & 3;
      int gn = n0 + row;
      if (GUARD) gn = (gn < N) ? gn : (N-1);
      int sc = cg ^ ((row&3) ^ ((row>>2)&3));
      const u16* gb = Bt + (size_t)gn*ldb + k0 + sc*8;
      __builtin_amdgcn_global_load_lds(
        (const __attribute__((address_space(1))) void*)gb,
        (__attribute__((address_space(3))) void*)&Bs[buf][slot*8], 16, 0, 0);
    }
  };

  auto comp = [&](int t){
    const int buf = t % 3;
    bf16x8 af[MF], bfr[NF];
    #pragma unroll
    for (int m=0;m<MF;m++){
      int row = wm*(MF*16) + m*16 + lr;
      af[m] = *reinterpret_cast<const bf16x8*>(&As[buf][row*32 + ce]);
    }
    #pragma unroll
    for (int n=0;n<NF;n++){
      int row = wn*(NF*16) + n*16 + lr;
      bfr[n] = *reinterpret_cast<const bf16x8*>(&Bs[buf][row*32 + ce]);
    }
    __builtin_amdgcn_s_setprio(1);
    #pragma unroll
    for (int m=0;m<MF;m++)
      #pragma unroll
      for (int n=0;n<NF;n++)
        acc[m][n] = __builtin_amdgcn_mfma_f32_16x16x32_bf16(af[m], bfr[n], acc[m][n], 0,0,0);
    __builtin_amdgcn_s_setprio(0);
  };

  const int nt = K >> 5;                 // >= 4 for all our shapes
  stage(0); stage(1);
  for (int t=0; t<nt; ++t){
    if (t+1 < nt) waitcnt_vm<LPS>();
    else          waitcnt_vm<0>();
    asm volatile("s_barrier" ::: "memory");
    if (t+2 < nt) stage(t+2);
    comp(t);
  }

  #pragma unroll
  for (int m=0;m<MF;m++){
    int row = m0 + wm*(MF*16) + m*16 + lq*4;
    #pragma unroll
    for (int n=0;n<NF;n++){
      int col = n0 + wn*(NF*16) + n*16 + lr;
      if (!GUARD || col < N){
        #pragma unroll
        for (int j=0;j<4;j++){
          float v = acc[m][n][j];
          size_t r = (size_t)(row+j);
          if (MODE == 0)      ((float*)Cp)[r*ldc + col] = v;
          else if (MODE == 1) ((u16*)Cp)[r*ldc + col] = f2bf(v);
          else {
            u16 bv = f2bf(v);
            if (col < 2048)      zb[r*2048 + col] = bv;
            else if (col < 4352) xb[r*2304 + (col-2048)] = bv;
            else                 db_[r*64 + (col-4352)] = bv;
          }
        }
      }
    }
  }
}

// ---------------- old 128-tile GEMM (kept for the skinny Dscal matmul) ------
template<int GUARD, int MODE>
__global__ __launch_bounds__(256) void gemm_bt(
    const u16* __restrict__ A, int lda,
    const u16* __restrict__ Bt, int ldb,
    void* __restrict__ Cp, int ldc,
    int M, int N, int K,
    u16* __restrict__ zb, u16* __restrict__ xb, u16* __restrict__ db_)
{
  __shared__ __align__(16) u16 As[128*64];
  __shared__ __align__(16) u16 Bs[128*64];
  const int tid  = threadIdx.x;
  const int wid  = tid >> 6;
  const int lane = tid & 63;
  const int nwg = gridDim.x * gridDim.y;
  const int bid = blockIdx.y * gridDim.x + blockIdx.x;
  const int q8  = nwg >> 3;
  const int swz = (nwg >= 8) ? ((bid & 7)*q8 + (bid >> 3)) : bid;
  const int m0 = (swz / gridDim.x) * 128;
  const int n0 = (swz % gridDim.x) * 128;
  const int wr = wid >> 1, wc = wid & 1;
  const int lq = lane >> 4, lr = lane & 15;

  f32x4 acc[4][4];
  #pragma unroll
  for (int m=0;m<4;m++)
    #pragma unroll
    for (int n=0;n<4;n++) acc[m][n] = (f32x4){0.f,0.f,0.f,0.f};

  const int srow = wid*32 + (lane>>3);
  const int scol = (lane&7)*8;

  for (int k0=0; k0<K; k0+=64){
    #pragma unroll
    for (int i=0;i<4;i++){
      const u16* ga = A + (size_t)(m0 + srow + i*8)*lda + k0 + scol;
      __builtin_amdgcn_global_load_lds(
        (const __attribute__((address_space(1))) void*)ga,
        (__attribute__((address_space(3))) void*)&As[(wid*32+i*8)*64], 16, 0, 0);
    }
    #pragma unroll
    for (int i=0;i<4;i++){
      int gn = n0 + srow + i*8;
      if (GUARD) gn = (gn < N) ? gn : (N-1);
      const u16* gb = Bt + (size_t)gn*ldb + k0 + scol;
      __builtin_amdgcn_global_load_lds(
        (const __attribute__((address_space(1))) void*)gb,
        (__attribute__((address_space(3))) void*)&Bs[(wid*32+i*8)*64], 16, 0, 0);
    }
    __syncthreads();
    #pragma unroll
    for (int kk=0;kk<2;kk++){
      bf16x8 af[4], bfr[4];
      #pragma unroll
      for (int m=0;m<4;m++)
        af[m] = *reinterpret_cast<const bf16x8*>(&As[(wr*64 + m*16 + lr)*64 + kk*32 + lq*8]);
      #pragma unroll
      for (int n=0;n<4;n++)
        bfr[n] = *reinterpret_cast<const bf16x8*>(&Bs[(wc*64 + n*16 + lr)*64 + kk*32 + lq*8]);
      #pragma unroll
      for (int m=0;m<4;m++)
        #pragma unroll
        for (int n=0;n<4;n++)
          acc[m][n] = __builtin_amdgcn_mfma_f32_16x16x32_bf16(af[m], bfr[n], acc[m][n], 0,0,0);
    }
    __syncthreads();
  }

  #pragma unroll
  for (int m=0;m<4;m++){
    int row = m0 + wr*64 + m*16 + lq*4;
    #pragma unroll
    for (int n=0;n<4;n++){
      int col = n0 + wc*64 + n*16 + lr;
      if (!GUARD || col < N){
        #pragma unroll
        for (int j=0;j<4;j++){
          float v = acc[m][n][j];
          size_t r = (size_t)(row+j);
          if (MODE == 0)      ((float*)Cp)[r*ldc + col] = v;
          else if (MODE == 1) ((u16*)Cp)[r*ldc + col] = f2bf(v);
          else {
            u16 bv = f2bf(v);
            if (col < 2048)      zb[r*2048 + col] = bv;
            else if (col < 4352) xb[r*2304 + (col-2048)] = bv;
            else                 db_[r*64 + (col-4352)] = bv;
          }
        }
      }
    }
  }
}

// ---------------- depthwise conv7 (SAME) + bias + SiLU -> bf16 ----------------
__global__ __launch_bounds__(256) void conv_silu(
    const u16* __restrict__ xbc, const u16* __restrict__ wtb,
    const float* __restrict__ bias, u16* __restrict__ xc)
{
  const int bid = blockIdx.x;
  const int sb  = (bid & 7)*1152 + (bid >> 3);
  const int idx = sb*256 + threadIdx.x;       // < 8192*288
  const int g   = idx % 288;
  const int row = idx / 288;
  const int l = row & 4095;
  const int c = g*8;
  float a[8];
  float4 b0 = *reinterpret_cast<const float4*>(&bias[c]);
  float4 b1 = *reinterpret_cast<const float4*>(&bias[c+4]);
  a[0]=b0.x; a[1]=b0.y; a[2]=b0.z; a[3]=b0.w;
  a[4]=b1.x; a[5]=b1.y; a[6]=b1.z; a[7]=b1.w;
  #pragma unroll
  for (int t=0;t<7;t++){
    int ls = l + t - 3;
    if (ls >= 0 && ls < 4096){
      bf16x8 v  = *reinterpret_cast<const bf16x8*>(&xbc[(size_t)(row + t - 3)*2304 + c]);
      bf16x8 wv = *reinterpret_cast<const bf16x8*>(&wtb[t*2304 + c]);
      #pragma unroll
      for (int j=0;j<8;j++) a[j] += bf2f((u16)v[j]) * bf2f((u16)wv[j]);
    }
  }
  bf16x8 o;
  #pragma unroll
  for (int j=0;j<8;j++){
    float s = a[j]/(1.f+__expf(-a[j]));
    o[j] = (short)f2bf(s);
  }
  *reinterpret_cast<bf16x8*>(&xc[(size_t)row*2304 + c]) = o;
}

// ================= chunked SSD scan (Q=64) =================
__global__ __launch_bounds__(256) void ssd_chunk(
    const u16* __restrict__ xc, const u16* __restrict__ dtb,
    const float* __restrict__ dt_bias, const float* __restrict__ A_log,
    u16* __restrict__ yP, u16* __restrict__ dB, float* __restrict__ csum, int dir)
{
  const int c  = blockIdx.x & 63;
  const int th = blockIdx.x >> 6;
  const int h  = th & 31;
  const int b  = th >> 5;
  const int tid = threadIdx.x;
  const int wid = tid >> 6;
  const int lane = tid & 63;
  const int lq = lane >> 4, lr = lane & 15;

  __shared__ __align__(16) u16 Cs[64*64];
  __shared__ __align__(16) u16 Bls[64*64];
  __shared__ __align__(16) u16 Xt[64*64];
  __shared__ __align__(16) u16 Gm[64*64];
  __shared__ __align__(16) u16 Bwt[64*64];
  __shared__ float cum[64], dtl[64];

  const float Ah = -__expf(A_log[h]);

  for (int e = tid; e < 512; e += 256){
    int i = e >> 3, g = e & 7;
    int l = dir ? (4095 - (c*64+i)) : (c*64+i);
    size_t rb = (size_t)(b*4096 + l)*2304;
    *reinterpret_cast<bf16x8*>(&Bls[i*64+g*8]) =
        *reinterpret_cast<const bf16x8*>(&xc[rb + 2048 + dir*128 + g*8]);
    *reinterpret_cast<bf16x8*>(&Cs[i*64+g*8]) =
        *reinterpret_cast<const bf16x8*>(&xc[rb + 2112 + dir*128 + g*8]);
  }
  for (int e = tid; e < 512; e += 256){
    int i = e & 63, g = e >> 6;
    int l = dir ? (4095 - (c*64+i)) : (c*64+i);
    bf16x8 xv = *reinterpret_cast<const bf16x8*>(&xc[(size_t)(b*4096+l)*2304 + (size_t)h*64 + g*8]);
    #pragma unroll
    for (int j=0;j<8;j++) Xt[(g*8+j)*64 + i] = (u16)xv[j];
  }
  if (tid < 64){
    int i = tid;
    int l = dir ? (4095 - (c*64+i)) : (c*64+i);
    float raw = bf2f(dtb[(size_t)(b*4096+l)*64 + dir*32 + h]) + dt_bias[h];
    float dte = (raw > 20.f) ? raw : log1pf(__expf(raw));
    dtl[i] = dte;
    float s = dte;
    #pragma unroll
    for (int off=1; off<64; off<<=1){
      float o = __shfl_up(s, off, 64);
      if (i >= off) s += o;
    }
    cum[i] = s;
    if (i == 63) csum[blockIdx.x] = s;
  }
  __syncthreads();

  f32x4 g4[4];
  #pragma unroll
  for (int n=0;n<4;n++) g4[n] = (f32x4){0.f,0.f,0.f,0.f};
  #pragma unroll
  for (int kk=0;kk<2;kk++){
    bf16x8 ca = *reinterpret_cast<const bf16x8*>(&Cs[(wid*16+lr)*64 + kk*32 + lq*8]);
    #pragma unroll
    for (int n=0;n<4;n++){
      bf16x8 bb = *reinterpret_cast<const bf16x8*>(&Bls[(n*16+lr)*64 + kk*32 + lq*8]);
      g4[n] = __builtin_amdgcn_mfma_f32_16x16x32_bf16(ca, bb, g4[n], 0,0,0);
    }
  }
  #pragma unroll
  for (int n=0;n<4;n++){
    #pragma unroll
    for (int r=0;r<4;r++){
      int gi = wid*16 + lq*4 + r;
      int gj = n*16 + lr;
      float wgt = (gj <= gi) ? __expf(Ah*(cum[gi]-cum[gj]))*dtl[gj] : 0.f;
      Gm[gi*64+gj] = f2bf(g4[n][r]*wgt);
    }
  }
  float ctot = cum[63];
  for (int e = tid; e < 512; e += 256){
    int j = e & 63, g = e >> 6;
    float wj = __expf(Ah*(ctot - cum[j])) * dtl[j];
    bf16x8 bv = *reinterpret_cast<const bf16x8*>(&Bls[j*64 + g*8]);
    #pragma unroll
    for (int nn=0;nn<8;nn++) Bwt[(g*8+nn)*64 + j] = f2bf(wj * bf2f((u16)bv[nn]));
  }
  __syncthreads();

  f32x4 yi[4], db4[4];
  #pragma unroll
  for (int n=0;n<4;n++){ yi[n] = (f32x4){0.f,0.f,0.f,0.f}; db4[n] = (f32x4){0.f,0.f,0.f,0.f}; }
  #pragma unroll
  for (int kk=0;kk<2;kk++){
    bf16x8 ga = *reinterpret_cast<const bf16x8*>(&Gm[(wid*16+lr)*64 + kk*32 + lq*8]);
    bf16x8 xa = *reinterpret_cast<const bf16x8*>(&Xt[(wid*16+lr)*64 + kk*32 + lq*8]);
    #pragma unroll
    for (int n=0;n<4;n++){
      bf16x8 xb = *reinterpret_cast<const bf16x8*>(&Xt[(n*16+lr)*64 + kk*32 + lq*8]);
      yi[n] = __builtin_amdgcn_mfma_f32_16x16x32_bf16(ga, xb, yi[n], 0,0,0);
      bf16x8 wb = *reinterpret_cast<const bf16x8*>(&Bwt[(n*16+lr)*64 + kk*32 + lq*8]);
      db4[n] = __builtin_amdgcn_mfma_f32_16x16x32_bf16(xa, wb, db4[n], 0,0,0);
    }
  }
  #pragma unroll
  for (int n=0;n<4;n++){
    #pragma unroll
    for (int r=0;r<4;r++){
      int i = wid*16 + lq*4 + r;
      yP[(size_t)(b*4096 + c*64 + i)*2048 + (size_t)h*64 + n*16 + lr] = f2bf(yi[n][r]);
    }
  }
  u16* dst = dB + (size_t)blockIdx.x*4096;
  #pragma unroll
  for (int n=0;n<4;n++){
    #pragma unroll
    for (int r=0;r<4;r++){
      int p = wid*16 + lq*4 + r;
      dst[p*64 + n*16 + lr] = f2bf(db4[n][r]);
    }
  }
}

// Pass B1: sequential h-chain over chunks, slot-shift in-place.
__global__ __launch_bounds__(256) void ssd_state(
    u16* __restrict__ dB, const float* __restrict__ csum,
    const float* __restrict__ A_log)
{
  const int q = blockIdx.x & 3;
  const int task = blockIdx.x >> 2;
  const int h = task & 31;
  const float Ah = -__expf(A_log[h]);
  const int p  = q*16 + (threadIdx.x >> 4);
  const int nb = (threadIdx.x & 15) * 4;
  float h0=0.f, h1=0.f, h2=0.f, h3=0.f;
  for (int c=0; c<63; ++c){
    float P = __expf(Ah * csum[task*64 + c]);
    u16* ptr = dB + ((size_t)(task*64 + c))*4096 + p*64 + nb;
    ushort4 dv = *reinterpret_cast<const ushort4*>(ptr);
    h0 = P*h0 + bf2f(dv.x);
    h1 = P*h1 + bf2f(dv.y);
    h2 = P*h2 + bf2f(dv.z);
    h3 = P*h3 + bf2f(dv.w);
    *reinterpret_cast<ushort4*>(ptr) = make_ushort4(f2bf(h0),f2bf(h1),f2bf(h2),f2bf(h3));
  }
}

// Pass B2: y += cd[i] * (C @ h_in^T). chunk 0 skipped.
__global__ __launch_bounds__(256) void ssd_yinter(
    const u16* __restrict__ xc, const u16* __restrict__ dtb,
    const float* __restrict__ dt_bias, const float* __restrict__ A_log,
    const u16* __restrict__ dB, u16* __restrict__ yP, int dir)
{
  const int c  = blockIdx.x & 63;
  if (c == 0) return;
  const int th = blockIdx.x >> 6;
  const int h  = th & 31;
  const int b  = th >> 5;
  const int tid = threadIdx.x;
  const int wid = tid >> 6;
  const int lane = tid & 63;
  const int lq = lane >> 4, lr = lane & 15;

  __shared__ __align__(16) u16 Cs[64*64];
  __shared__ __align__(16) u16 Hs[64*64];
  __shared__ float cum[64];

  const float Ah = -__expf(A_log[h]);

  for (int e = tid; e < 512; e += 256){
    int i = e >> 3, g = e & 7;
    int l = dir ? (4095 - (c*64+i)) : (c*64+i);
    *reinterpret_cast<bf16x8*>(&Cs[i*64+g*8]) =
        *reinterpret_cast<const bf16x8*>(&xc[(size_t)(b*4096+l)*2304 + 2112 + dir*128 + g*8]);
    *reinterpret_cast<bf16x8*>(&Hs[e*8]) =
        *reinterpret_cast<const bf16x8*>(&dB[(size_t)(blockIdx.x-1)*4096 + e*8]);
  }
  if (tid < 64){
    int i = tid;
    int l = dir ? (4095 - (c*64+i)) : (c*64+i);
    float raw = bf2f(dtb[(size_t)(b*4096+l)*64 + dir*32 + h]) + dt_bias[h];
    float dte = (raw > 20.f) ? raw : log1pf(__expf(raw));
    float s = dte;
    #pragma unroll
    for (int off=1; off<64; off<<=1){
      float o = __shfl_up(s, off, 64);
      if (i >= off) s += o;
    }
    cum[i] = s;
  }
  __syncthreads();

  f32x4 acc[4];
  #pragma unroll
  for (int n=0;n<4;n++) acc[n] = (f32x4){0.f,0.f,0.f,0.f};
  #pragma unroll
  for (int kk=0;kk<2;kk++){
    bf16x8 ca = *reinterpret_cast<const bf16x8*>(&Cs[(wid*16+lr)*64 + kk*32 + lq*8]);
    #pragma unroll
    for (int n=0;n<4;n++){
      bf16x8 hb = *reinterpret_cast<const bf16x8*>(&Hs[(n*16+lr)*64 + kk*32 + lq*8]);
      acc[n] = __builtin_amdgcn_mfma_f32_16x16x32_bf16(ca, hb, acc[n], 0,0,0);
    }
  }
  #pragma unroll
  for (int n=0;n<4;n++){
    #pragma unroll
    for (int r=0;r<4;r++){
      int i = wid*16 + lq*4 + r;
      float cd = __expf(Ah*cum[i]);
      size_t a = (size_t)(b*4096 + c*64 + i)*2048 + (size_t)h*64 + n*16 + lr;
      yP[a] = f2bf(bf2f(yP[a]) + cd*acc[n][r]);
    }
  }
}

// ---------------- fuse: y-combine(shift/flip) + D*x + RMSNorm + SiLU(z) ------
__global__ __launch_bounds__(256) void fuse_rms(
    const u16* __restrict__ ypF, const u16* __restrict__ ypB,
    const u16* __restrict__ xc, const u16* __restrict__ zbuf,
    u16* __restrict__ un,
    const float* __restrict__ Dscal, const float* __restrict__ D_b,
    const float* __restrict__ rms_w)
{
  const int row = blockIdx.x;
  const int l = row & 4095;
  const int tid = threadIdx.x;
  const int c = tid*8;
  const int hh = tid >> 3;
  float v[8]; float ss = 0.f;
  const bool hasF = (l >= 1);
  const bool hasB = (l <= 4094);
  bf16x8 yf, yb;
  if (hasF) yf = *reinterpret_cast<const bf16x8*>(&ypF[(size_t)(row-1)*2048 + c]);
  if (hasB) yb = *reinterpret_cast<const bf16x8*>(&ypB[(size_t)(row + 4094 - 2*l)*2048 + c]);
  bf16x8 xv = *reinterpret_cast<const bf16x8*>(&xc[(size_t)row*2304 + c]);
  const float dsc = Dscal[(size_t)row*32 + hh] + D_b[hh];
  #pragma unroll
  for (int i=0;i<8;i++){
    float y = hasF ? bf2f((u16)yf[i]) : 0.f;
    if (hasB) y += bf2f((u16)yb[i]);
    y += dsc * bf2f((u16)xv[i]);
    v[i] = y;
    ss += y*y;
  }
  #pragma unroll
  for (int o=1;o<64;o<<=1) ss += __shfl_xor(ss, o, 64);
  __shared__ float sred[4];
  if ((tid & 63) == 0) sred[tid>>6] = ss;
  __syncthreads();
  float rstd = rsqrtf((sred[0]+sred[1]+sred[2]+sred[3]) * (1.f/2048.f) + 1e-5f);
  bf16x8 zv = *reinterpret_cast<const bf16x8*>(&zbuf[(size_t)row*2048 + c]);
  bf16x8 o;
  #pragma unroll
  for (int i=0;i<8;i++){
    float z = bf2f((u16)zv[i]);
    float sz = z / (1.f + __expf(-z));
    o[i] = (short)f2bf(v[i]*rstd*rms_w[c+i]*sz);
  }
  *reinterpret_cast<bf16x8*>(&un[(size_t)row*2048 + c]) = o;
}

extern "C" void kernel_launch(void* const* d_in, const int* in_sizes, int n_in,
                              void* d_out, int out_size, void* d_ws, size_t ws_size,
                              hipStream_t stream)
{
  const float* u       = (const float*)d_in[0];
  const float* w_in    = (const float*)d_in[1];
  const float* conv_w  = (const float*)d_in[2];
  const float* conv_b  = (const float*)d_in[3];
  const float* dt_bias = (const float*)d_in[4];
  const float* A_log   = (const float*)d_in[5];
  const float* D_w     = (const float*)d_in[6];
  const float* D_b     = (const float*)d_in[7];
  const float* rms_w   = (const float*)d_in[8];
  const float* w_out   = (const float*)d_in[9];
  float* out = (float*)d_out;
  (void)in_sizes; (void)n_in; (void)out_size; (void)ws_size;

  char* ws = (char*)d_ws;
  u16*   zbuf = (u16*)(ws);                         // 8192x2048 bf16
  u16*   xbc  = (u16*)(ws + 33554432);              // 8192x2304 bf16 (dead after conv -> dB -> un)
  u16*   dtbuf= (u16*)(ws + 71303168);              // 8192x64  bf16
  u16*   xc   = (u16*)(ws + 72351744);              // 8192x2304 bf16
  u16*   ypF  = (u16*)(ws + 110100480);             // 8192x2048 bf16
  u16*   ypB  = (u16*)(ws + 143654912);             // 8192x2048 bf16
  float* Dsc  = (float*)(ws + 177209344);           // 8192x32 f32
  u16*   w2b  = (u16*)(ws + 178257920);             // 1024x2048 bf16
  u16*   dwb  = (u16*)(ws + 182452224);             // 32x2048 bf16
  float* csum = (float*)(ws + 182583296);           // 2 x 4096 f32
  u16*   wtb  = (u16*)(ws + 182616064);             // 7x2304 bf16
  // aliases
  u16*   ub   = ypF;
  u16*   w1b  = ypF + (size_t)8192*1024;
  u16*   dB   = xbc;
  u16*   un   = xbc;

  cvt_f32_bf16<<<8192,256,0,stream>>>(u,     ub,  8192*1024/4);
  cvt_f32_bf16<<<4416,256,0,stream>>>(w_in,  w1b, 4416*1024/4);
  cvt_f32_bf16<<<2048,256,0,stream>>>(w_out, w2b, 1024*2048/4);
  cvt_f32_bf16<<<64,  256,0,stream>>>(D_w,   dwb, 32*2048/4);
  conv_prep<<<63,256,0,stream>>>(conv_w, wtb);

  // zxBCdt = u @ in_proj_w^T  (split into zbuf / xbc / dtbuf)
  // 128x128 tile, 3-buf safe pipeline, 48KB LDS -> 3 blocks/CU;
  // m-fastest XCD mapping: B-tile stays in per-XCD L2 across 8 m-blocks.
  gemm_p<1,2,128,128,2,2><<<dim3(35,64),256,0,stream>>>(ub,1024, w1b,1024, nullptr,0,
                                                        8192,4416,1024, zbuf, xbc, dtbuf);
  // depthwise conv + silu -> xc
  conv_silu<<<9216,256,0,stream>>>(xbc, wtb, conv_b, xc);
  // Dscal = x_og @ D_w^T  (f32)
  gemm_bt<1,0><<<dim3(1,64),256,0,stream>>>(xc,2304, dwb,2048, Dsc,32,
                                            8192,32,2048, nullptr,nullptr,nullptr);
  // chunked SSD scan, per direction
  for (int dir=0; dir<2; ++dir){
    u16* yP = dir ? ypB : ypF;
    ssd_chunk <<<4096,256,0,stream>>>(xc, dtbuf, dt_bias, A_log, yP, dB, csum + dir*4096, dir);
    ssd_state <<<256, 256,0,stream>>>(dB, csum + dir*4096, A_log);
    ssd_yinter<<<4096,256,0,stream>>>(xc, dtbuf, dt_bias, A_log, dB, yP, dir);
  }
  // combine + D path + RMS + gate -> un
  fuse_rms<<<8192,256,0,stream>>>(ypF, ypB, xc, zbuf, un, Dsc, D_b, rms_w);
  // out = un @ outproj_w^T  (f32)
  // 128x64 tile -> grid 1024 blocks = 4 blocks/CU (36KB LDS), one tail-free
  // round (r10: 512 blocks = 2/CU was the gemm2 occupancy wall, 109us).
  gemm_p<0,0,128,64,2,2><<<dim3(16,64),256,0,stream>>>(un,2048, w2b,2048, out,1024,
                                                       8192,1024,2048, nullptr,nullptr,nullptr);
}